// Round 1
// 838.766 us; speedup vs baseline: 1.0637x; 1.0637x over previous
//
#include <hip/hip_runtime.h>

// ---------------------------------------------------------------------------
// AttentionLayer fused implementation for MI355X (gfx950)  -- Round 3
// D=H=1024, B=128, R=512, M=B*R=65536
//
// R3 changes vs R2 (theory: score_gemm was latency-bound on the per-K-step
// fp32 A-load -> cvt -> ds_write chain; MfmaUtil 12.7%):
//  * conv_k: one-shot V fp32 -> bf16 (Vb, 128 MB in workspace).
//  * score_gemm_k: pure m97-structure GEMM -- BOTH operands staged with
//    global_load_lds width=16 into XOR-octet-swizzled linear LDS; no
//    register staging, no cvt, no ds_write in the hot loop. DMA issued at
//    step k drains at the END of step k (full step of latency hiding).
//  * Fallback to the R2 register-staging kernel if ws_size < 140 MB.
// ---------------------------------------------------------------------------

typedef __bf16 bf16x8 __attribute__((ext_vector_type(8)));
typedef float floatx4 __attribute__((ext_vector_type(4)));

__device__ __forceinline__ float tanh_fast(float x) {
    x = fminf(10.0f, fmaxf(-10.0f, x));
    float e = exp2f(x * 2.885390081777927f);
    return (e - 1.0f) * __builtin_amdgcn_rcpf(e + 1.0f);
}

// ---------------- K0: convert V fp32 -> bf16 ------------------------------
// 67,108,864 elements, 8 per thread: 32B coalesced read, 16B coalesced write.
__global__ __launch_bounds__(256) void conv_k(
    const float* __restrict__ V, __bf16* __restrict__ Vb) {
    const size_t i = ((size_t)blockIdx.x * 256 + threadIdx.x) * 8;
    const float4 a = *reinterpret_cast<const float4*>(V + i);
    const float4 b = *reinterpret_cast<const float4*>(V + i + 4);
    bf16x8 o;
    o[0] = (__bf16)a.x; o[1] = (__bf16)a.y;
    o[2] = (__bf16)a.z; o[3] = (__bf16)a.w;
    o[4] = (__bf16)b.x; o[5] = (__bf16)b.y;
    o[6] = (__bf16)b.z; o[7] = (__bf16)b.w;
    *reinterpret_cast<bf16x8*>(Vb + i) = o;
}

// ---------------- K1: transpose + convert Wv -> WvT (bf16) ----------------
__global__ __launch_bounds__(256) void wvt_kernel(
    const float* __restrict__ Wv, __bf16* __restrict__ WvT) {
    __shared__ float tile[64][65];
    const int k0 = blockIdx.x * 64, n0 = blockIdx.y * 64;
    const int c = threadIdx.x & 63, r = threadIdx.x >> 6;  // 4 rows/pass
#pragma unroll
    for (int i = 0; i < 16; ++i)
        tile[r + i * 4][c] = Wv[(size_t)(k0 + r + i * 4) * 1024 + n0 + c];
    __syncthreads();
#pragma unroll
    for (int i = 0; i < 16; ++i)
        WvT[(size_t)(n0 + r + i * 4) * 1024 + k0 + c] =
            (__bf16)tile[c][r + i * 4];
}

// ---------------- small fp32 GEMM: C[128,1024] = act(A@W + b) -------------
__global__ __launch_bounds__(512) void small_gemm_k(
    const float* __restrict__ A0, const float* __restrict__ W0,
    const float* __restrict__ b0, float* __restrict__ C0, int act0,
    const float* __restrict__ A1, const float* __restrict__ W1,
    const float* __restrict__ b1, float* __restrict__ C1, int act1) {
    const float* A; const float* W; const float* bs; float* C; int act;
    if (blockIdx.z == 0) { A = A0; W = W0; bs = b0; C = C0; act = act0; }
    else                 { A = A1; W = W1; bs = b1; C = C1; act = act1; }
    __shared__ float red[3][8][128];
    const int tid = threadIdx.x;
    const int nl = tid & 127, kq = tid >> 7;
    const int n = blockIdx.x * 128 + nl;
    const int m0 = blockIdx.y * 8;
    const float* Ab = A + m0 * 1024;
    float acc[8] = {};
    const int kbeg = kq * 256, kend = kbeg + 256;
#pragma unroll 4
    for (int k = kbeg; k < kend; ++k) {
        float w = W[(size_t)k * 1024 + n];
#pragma unroll
        for (int mi = 0; mi < 8; ++mi)
            acc[mi] = fmaf(Ab[mi * 1024 + k], w, acc[mi]);
    }
    if (kq > 0) {
#pragma unroll
        for (int mi = 0; mi < 8; ++mi) red[kq - 1][mi][nl] = acc[mi];
    }
    __syncthreads();
    if (kq == 0) {
        float bias = bs[n];
#pragma unroll
        for (int mi = 0; mi < 8; ++mi) {
            float v = acc[mi] + red[0][mi][nl] + red[1][mi][nl] +
                      red[2][mi][nl] + bias;
            if (act == 1) v = fmaxf(v, 0.0f);
            else if (act == 2) v = tanh_fast(v);
            C[(size_t)(m0 + mi) * 1024 + n] = v;
        }
    }
}

// ---------------- K5: fused score GEMM (full-DMA m97 structure) -----------
// 128x128 tile, BK=32, 4 waves x (64x64 via 4x4 mfma_f32_16x16x32_bf16).
// Both A (Vb) and B (WvT) staged via global_load_lds w=16 into linear LDS;
// k-octet XOR swizzle applied on the GLOBAL source address and mirrored on
// the ds_read_b128 fragment offset (involution -> round-trips correctly).
// One barrier per K-step; DMA for step k+1 issued before step k's MFMAs.
// Epilogue folds bv/relu/h_att/tanh/Wal-dot, shuffle-reduces 16 n-lanes,
// atomicAdds into scores.
__global__ __launch_bounds__(256, 3) void score_gemm_k(
    const __bf16* __restrict__ Vb, const __bf16* __restrict__ WvT,
    const float* __restrict__ bv, const float* __restrict__ h_att,
    const float* __restrict__ Wal, float* __restrict__ scores) {
    __shared__ __bf16 As[2][128 * 32];
    __shared__ __bf16 Bs[2][128 * 32];

    const int tid = threadIdx.x;
    const int bid = blockIdx.x;
    const int xcd = bid & 7;
    const int j = bid >> 3;
    const int mtile = xcd * 64 + (j >> 3);   // 0..511
    const int ntile = j & 7;                 // 0..7
    const int m0 = mtile * 128, n0 = ntile * 128;
    const int wid = tid >> 6, lane = tid & 63;
    const int wm = wid & 1, wn = wid >> 1;
    const int lcol = lane & 15, quad = lane >> 4;

    floatx4 acc[4][4] = {};

    // granule g (0..511): row=g>>2, lds-octet=g&3, src-octet=(g&3)^((row>>1)&3)
    // g0 = tid, g1 = 256+tid (row+64; (row>>1)&3 unchanged -> same kg).
    const int grow = tid >> 2;
    const int kg = (tid & 3) ^ ((grow >> 1) & 3);
    const __bf16* ap0 = Vb + (size_t)(m0 + grow) * 1024 + kg * 8;
    const __bf16* bp0 = WvT + (size_t)(n0 + grow) * 1024 + kg * 8;

    auto dma = [&](int buf, int k0) {
        __builtin_amdgcn_global_load_lds(
            (const __attribute__((address_space(1))) void*)(ap0 + k0),
            (__attribute__((address_space(3))) void*)(&As[buf][tid * 8]),
            16, 0, 0);
        __builtin_amdgcn_global_load_lds(
            (const __attribute__((address_space(1))) void*)(ap0 + 64 * 1024 + k0),
            (__attribute__((address_space(3))) void*)(&As[buf][(256 + tid) * 8]),
            16, 0, 0);
        __builtin_amdgcn_global_load_lds(
            (const __attribute__((address_space(1))) void*)(bp0 + k0),
            (__attribute__((address_space(3))) void*)(&Bs[buf][tid * 8]),
            16, 0, 0);
        __builtin_amdgcn_global_load_lds(
            (const __attribute__((address_space(1))) void*)(bp0 + 64 * 1024 + k0),
            (__attribute__((address_space(3))) void*)(&Bs[buf][(256 + tid) * 8]),
            16, 0, 0);
    };

    // ---- prologue
    dma(0, 0);

    // fragment LDS element offsets (row-swizzled octets), loop-invariant
    int aoff[4], boff[4];
#pragma unroll
    for (int i = 0; i < 4; ++i) {
        int r = wm * 64 + i * 16 + lcol;
        aoff[i] = r * 32 + ((quad ^ ((r >> 1) & 3)) * 8);
        int n = wn * 64 + i * 16 + lcol;
        boff[i] = n * 32 + ((quad ^ ((n >> 1) & 3)) * 8);
    }
    __syncthreads();

    for (int kk = 0; kk < 32; ++kk) {
        const int cur = kk & 1, nxt = cur ^ 1;
        if (kk < 31) dma(nxt, (kk + 1) * 32);   // in flight across this step
        bf16x8 af[4], bfr[4];
#pragma unroll
        for (int i = 0; i < 4; ++i) {
            af[i] = *reinterpret_cast<const bf16x8*>(&As[cur][aoff[i]]);
            bfr[i] = *reinterpret_cast<const bf16x8*>(&Bs[cur][boff[i]]);
        }
#pragma unroll
        for (int mi = 0; mi < 4; ++mi)
#pragma unroll
            for (int ni = 0; ni < 4; ++ni)
                acc[mi][ni] = __builtin_amdgcn_mfma_f32_16x16x32_bf16(
                    af[mi], bfr[ni], acc[mi][ni], 0, 0, 0);
        __syncthreads();   // drains DMA(nxt) for next step
    }

    // ---- epilogue: fused score partials ----
    const int b = m0 >> 9;
    float wal[4], hat[4], bvv[4];
#pragma unroll
    for (int ni = 0; ni < 4; ++ni) {
        int n = n0 + wn * 64 + ni * 16 + lcol;
        wal[ni] = Wal[n];
        hat[ni] = h_att[b * 1024 + n];
        bvv[ni] = bv[n];
    }
    float p[16];
#pragma unroll
    for (int mi = 0; mi < 4; ++mi) {
#pragma unroll
        for (int rg = 0; rg < 4; ++rg) {
            float s = 0.f;
#pragma unroll
            for (int ni = 0; ni < 4; ++ni) {
                float x = acc[mi][ni][rg] + bvv[ni];
                x = fmaxf(x, 0.f);
                s = fmaf(wal[ni], tanh_fast(x + hat[ni]), s);
            }
            p[mi * 4 + rg] = s;
        }
    }
#pragma unroll
    for (int off = 1; off < 16; off <<= 1) {
#pragma unroll
        for (int i = 0; i < 16; ++i) p[i] += __shfl_xor(p[i], off, 64);
    }
    if (lcol == 0) {
#pragma unroll
        for (int mi = 0; mi < 4; ++mi)
#pragma unroll
            for (int rg = 0; rg < 4; ++rg) {
                int row = m0 + wm * 64 + mi * 16 + quad * 4 + rg;
                atomicAdd(&scores[b * 513 + (row & 511)], p[mi * 4 + rg]);
            }
    }
}

// ---------------- K5fb: R2 register-staging fallback (fp32 V) -------------
__global__ __launch_bounds__(256, 3) void score_gemm_fb(
    const float* __restrict__ V, const __bf16* __restrict__ WvT,
    const float* __restrict__ bv, const float* __restrict__ h_att,
    const float* __restrict__ Wal, float* __restrict__ scores) {
    __shared__ __bf16 As[2][128 * 40];
    __shared__ __bf16 Bs[2][128 * 32];

    const int tid = threadIdx.x;
    const int bid = blockIdx.x;
    const int xcd = bid & 7;
    const int j = bid >> 3;
    const int mtile = xcd * 64 + (j >> 3);
    const int ntile = j & 7;
    const int m0 = mtile * 128, n0 = ntile * 128;
    const int wid = tid >> 6, lane = tid & 63;
    const int wm = wid & 1, wn = wid >> 1;
    const int lcol = lane & 15, quad = lane >> 4;

    floatx4 acc[4][4] = {};

    const int am = tid >> 1;
    const int ak = (tid & 1) * 16;
    const float* aptr = V + (size_t)(m0 + am) * 1024 + ak;

    const int g0n = tid >> 2, g0ks = tid & 3;
    const int g1n = (256 + tid) >> 2, g1ks = tid & 3;
    const int g0kg = g0ks ^ ((g0n >> 1) & 3);
    const int g1kg = g1ks ^ ((g1n >> 1) & 3);
    const __bf16* bp0 = WvT + (size_t)(n0 + g0n) * 1024 + g0kg * 8;
    const __bf16* bp1 = WvT + (size_t)(n0 + g1n) * 1024 + g1kg * 8;

    auto stage_A = [&](int buf, float4 f0, float4 f1, float4 f2, float4 f3) {
        bf16x8 u0, u1;
        u0[0] = (__bf16)f0.x; u0[1] = (__bf16)f0.y;
        u0[2] = (__bf16)f0.z; u0[3] = (__bf16)f0.w;
        u0[4] = (__bf16)f1.x; u0[5] = (__bf16)f1.y;
        u0[6] = (__bf16)f1.z; u0[7] = (__bf16)f1.w;
        u1[0] = (__bf16)f2.x; u1[1] = (__bf16)f2.y;
        u1[2] = (__bf16)f2.z; u1[3] = (__bf16)f2.w;
        u1[4] = (__bf16)f3.x; u1[5] = (__bf16)f3.y;
        u1[6] = (__bf16)f3.z; u1[7] = (__bf16)f3.w;
        __bf16* awr = &As[buf][am * 40 + ak];
        *reinterpret_cast<bf16x8*>(awr) = u0;
        *reinterpret_cast<bf16x8*>(awr + 8) = u1;
    };
    auto dma_B = [&](int buf, int k0) {
        __builtin_amdgcn_global_load_lds(
            (const __attribute__((address_space(1))) void*)(bp0 + k0),
            (__attribute__((address_space(3))) void*)(&Bs[buf][tid * 8]),
            16, 0, 0);
        __builtin_amdgcn_global_load_lds(
            (const __attribute__((address_space(1))) void*)(bp1 + k0),
            (__attribute__((address_space(3))) void*)(&Bs[buf][(256 + tid) * 8]),
            16, 0, 0);
    };

    dma_B(0, 0);
    {
        const float4* fp = reinterpret_cast<const float4*>(aptr);
        stage_A(0, fp[0], fp[1], fp[2], fp[3]);
    }
    __syncthreads();

    for (int kk = 0; kk < 32; ++kk) {
        const int cur = kk & 1, nxt = cur ^ 1;
        float4 f0, f1, f2, f3;
        const bool pf = (kk < 31);
        if (pf) {
            dma_B(nxt, (kk + 1) * 32);
            const float4* fp =
                reinterpret_cast<const float4*>(aptr + (kk + 1) * 32);
            f0 = fp[0]; f1 = fp[1]; f2 = fp[2]; f3 = fp[3];
        }
        bf16x8 af[4], bfr[4];
#pragma unroll
        for (int mi = 0; mi < 4; ++mi)
            af[mi] = *reinterpret_cast<const bf16x8*>(
                &As[cur][(wm * 64 + mi * 16 + lcol) * 40 + quad * 8]);
#pragma unroll
        for (int ni = 0; ni < 4; ++ni) {
            int n = wn * 64 + ni * 16 + lcol;
            int ks = quad ^ ((n >> 1) & 3);
            bfr[ni] = *reinterpret_cast<const bf16x8*>(
                &Bs[cur][n * 32 + ks * 8]);
        }
#pragma unroll
        for (int mi = 0; mi < 4; ++mi)
#pragma unroll
            for (int ni = 0; ni < 4; ++ni)
                acc[mi][ni] = __builtin_amdgcn_mfma_f32_16x16x32_bf16(
                    af[mi], bfr[ni], acc[mi][ni], 0, 0, 0);
        if (pf) stage_A(nxt, f0, f1, f2, f3);
        __syncthreads();
    }

    const int b = m0 >> 9;
    float wal[4], hat[4], bvv[4];
#pragma unroll
    for (int ni = 0; ni < 4; ++ni) {
        int n = n0 + wn * 64 + ni * 16 + lcol;
        wal[ni] = Wal[n];
        hat[ni] = h_att[b * 1024 + n];
        bvv[ni] = bv[n];
    }
    float p[16];
#pragma unroll
    for (int mi = 0; mi < 4; ++mi) {
#pragma unroll
        for (int rg = 0; rg < 4; ++rg) {
            float s = 0.f;
#pragma unroll
            for (int ni = 0; ni < 4; ++ni) {
                float x = acc[mi][ni][rg] + bvv[ni];
                x = fmaxf(x, 0.f);
                s = fmaf(wal[ni], tanh_fast(x + hat[ni]), s);
            }
            p[mi * 4 + rg] = s;
        }
    }
#pragma unroll
    for (int off = 1; off < 16; off <<= 1) {
#pragma unroll
        for (int i = 0; i < 16; ++i) p[i] += __shfl_xor(p[i], off, 64);
    }
    if (lcol == 0) {
#pragma unroll
        for (int mi = 0; mi < 4; ++mi)
#pragma unroll
            for (int rg = 0; rg < 4; ++rg) {
                int row = m0 + wm * 64 + mi * 16 + quad * 4 + rg;
                atomicAdd(&scores[b * 513 + (row & 511)], p[mi * 4 + rg]);
            }
    }
}

// ---------------- K6: scores[b][512] from s_att/h_att ---------------------
__global__ __launch_bounds__(256) void lastrow_k(
    const float* __restrict__ s_att, const float* __restrict__ h_att,
    const float* __restrict__ Wal, float* __restrict__ scores) {
    int b = blockIdx.x, tid = threadIdx.x;
    float s = 0.f;
    for (int h = tid; h < 1024; h += 256)
        s += Wal[h] * tanh_fast(s_att[b * 1024 + h] + h_att[b * 1024 + h]);
#pragma unroll
    for (int off = 32; off >= 1; off >>= 1) s += __shfl_xor(s, off, 64);
    __shared__ float red[4];
    if ((tid & 63) == 0) red[tid >> 6] = s;
    __syncthreads();
    if (tid == 0) scores[b * 513 + 512] = red[0] + red[1] + red[2] + red[3];
}

// ---------------- K7: softmax over 513 ------------------------------------
__global__ __launch_bounds__(256) void softmax_k(
    const float* __restrict__ scores, float* __restrict__ alpha) {
    int b = blockIdx.x, tid = threadIdx.x;
    const float* s = scores + b * 513;
    float v0 = s[tid];
    float v1 = s[tid + 256];
    float v2 = (tid == 0) ? s[512] : -1e30f;
    float m = fmaxf(v0, fmaxf(v1, v2));
#pragma unroll
    for (int off = 32; off >= 1; off >>= 1) m = fmaxf(m, __shfl_xor(m, off, 64));
    __shared__ float red[4];
    int w = tid >> 6;
    if ((tid & 63) == 0) red[w] = m;
    __syncthreads();
    m = fmaxf(fmaxf(red[0], red[1]), fmaxf(red[2], red[3]));
    const float L2E = 1.4426950408889634f;
    float e0 = exp2f((v0 - m) * L2E);
    float e1 = exp2f((v1 - m) * L2E);
    float e2 = (tid == 0) ? exp2f((v2 - m) * L2E) : 0.f;
    float sum = e0 + e1 + e2;
#pragma unroll
    for (int off = 32; off >= 1; off >>= 1) sum += __shfl_xor(sum, off, 64);
    __syncthreads();
    if ((tid & 63) == 0) red[w] = sum;
    __syncthreads();
    sum = red[0] + red[1] + red[2] + red[3];
    float inv = 1.0f / sum;
    float* a = alpha + b * 513;
    a[tid] = e0 * inv;
    a[tid + 256] = e1 * inv;
    if (tid == 0) a[512] = e2 * inv;
}

// ---------------- K8: context + h_proj ------------------------------------
__global__ __launch_bounds__(256) void ctx_k(
    const float* __restrict__ V, const float* __restrict__ alpha,
    const float* __restrict__ s_proj, const float* __restrict__ h_proj,
    float* __restrict__ ctxsum) {
    const int b = blockIdx.x, dq = blockIdx.y;
    const int tid = threadIdx.x;
    const int dl = tid & 63, rq = tid >> 6;
    __shared__ float sal[513];
    __shared__ float red[3][64][4];
    for (int i = tid; i < 513; i += 256) sal[i] = alpha[b * 513 + i];
    __syncthreads();
    const int d0 = dq * 256 + dl * 4;
    const float* vp = V + ((size_t)b * 512 + rq * 128) * 1024 + d0;
    float a0 = 0, a1 = 0, a2 = 0, a3 = 0;
#pragma unroll 8
    for (int r = 0; r < 128; ++r) {
        float al = sal[rq * 128 + r];
        const float4 vv = *reinterpret_cast<const float4*>(vp + (size_t)r * 1024);
        a0 = fmaf(al, vv.x, a0); a1 = fmaf(al, vv.y, a1);
        a2 = fmaf(al, vv.z, a2); a3 = fmaf(al, vv.w, a3);
    }
    if (rq > 0) {
        red[rq - 1][dl][0] = a0; red[rq - 1][dl][1] = a1;
        red[rq - 1][dl][2] = a2; red[rq - 1][dl][3] = a3;
    }
    __syncthreads();
    if (rq == 0) {
#pragma unroll
        for (int q = 0; q < 3; ++q) {
            a0 += red[q][dl][0]; a1 += red[q][dl][1];
            a2 += red[q][dl][2]; a3 += red[q][dl][3];
        }
        float4 sp = *reinterpret_cast<const float4*>(s_proj + b * 1024 + d0);
        float4 hp = *reinterpret_cast<const float4*>(h_proj + b * 1024 + d0);
        float aR = sal[512];
        float4 o;
        o.x = fmaf(aR, sp.x, a0) + hp.x;
        o.y = fmaf(aR, sp.y, a1) + hp.y;
        o.z = fmaf(aR, sp.z, a2) + hp.z;
        o.w = fmaf(aR, sp.w, a3) + hp.w;
        *reinterpret_cast<float4*>(ctxsum + b * 1024 + d0) = o;
    }
}

// ---------------------------------------------------------------------------
extern "C" void kernel_launch(void* const* d_in, const int* in_sizes, int n_in,
                              void* d_out, int out_size, void* d_ws,
                              size_t ws_size, hipStream_t stream) {
    const float* V   = (const float*)d_in[0];
    const float* s_t = (const float*)d_in[1];
    const float* h_t = (const float*)d_in[2];
    const float* Wv  = (const float*)d_in[3];
    const float* bv  = (const float*)d_in[4];
    const float* Wsp = (const float*)d_in[5];
    const float* bsp = (const float*)d_in[6];
    const float* Wsa = (const float*)d_in[7];
    const float* bsa = (const float*)d_in[8];
    const float* Whp = (const float*)d_in[9];
    const float* bhp = (const float*)d_in[10];
    const float* Wha = (const float*)d_in[11];
    const float* bha = (const float*)d_in[12];
    const float* Wal = (const float*)d_in[13];
    // d_in[14] = bal: softmax-invariant constant -> dropped
    const float* Wcp = (const float*)d_in[15];
    const float* bcp = (const float*)d_in[16];
    float* out = (float*)d_out;

    const size_t VB_BYTES = (size_t)128 * 512 * 1024 * 2;  // 128 MB
    const size_t SMALL_BYTES = 5242880 + 64;               // ~5.25 MB tail
    const bool big = ws_size >= VB_BYTES + SMALL_BYTES;

    char* ws = (char*)d_ws;
    __bf16* Vb = (__bf16*)ws;                    // 128 MB (big path only)
    char* base = big ? (ws + VB_BYTES) : ws;
    __bf16* WvT   = (__bf16*)(base + 0);         // 2 MB
    float* s_proj = (float*)(base + 2097152);    // 512 KB
    float* h_proj = (float*)(base + 2621440);    // 512 KB
    float* s_att  = (float*)(base + 3145728);    // 512 KB
    float* h_att  = (float*)(base + 3670016);    // 512 KB
    float* scores = (float*)(base + 4194304);    // 262656 B
    float* alpha  = (float*)(base + 4456960);    // 262656 B
    float* ctxsum = (float*)(base + 4719616);    // 512 KB

    if (big)
        hipLaunchKernelGGL(conv_k, dim3(32768), dim3(256), 0, stream, V, Vb);
    hipLaunchKernelGGL(wvt_kernel, dim3(16, 16), dim3(256), 0, stream, Wv, WvT);
    hipLaunchKernelGGL(small_gemm_k, dim3(8, 16, 2), dim3(512), 0, stream,
                       s_t, Wsp, bsp, s_proj, 1,
                       h_t, Whp, bhp, h_proj, 2);
    hipLaunchKernelGGL(small_gemm_k, dim3(8, 16, 2), dim3(512), 0, stream,
                       s_proj, Wsa, bsa, s_att, 0,
                       h_proj, Wha, bha, h_att, 0);
    (void)hipMemsetAsync(scores, 0, 128 * 513 * sizeof(float), stream);
    if (big)
        hipLaunchKernelGGL(score_gemm_k, dim3(4096), dim3(256), 0, stream,
                           Vb, WvT, bv, h_att, Wal, scores);
    else
        hipLaunchKernelGGL(score_gemm_fb, dim3(4096), dim3(256), 0, stream,
                           V, WvT, bv, h_att, Wal, scores);
    hipLaunchKernelGGL(lastrow_k, dim3(128), dim3(256), 0, stream,
                       s_att, h_att, Wal, scores);
    hipLaunchKernelGGL(softmax_k, dim3(128), dim3(256), 0, stream,
                       scores, alpha);
    hipLaunchKernelGGL(ctx_k, dim3(128, 4), dim3(256), 0, stream,
                       V, alpha, s_proj, h_proj, ctxsum);
    hipLaunchKernelGGL(small_gemm_k, dim3(8, 16, 1), dim3(512), 0, stream,
                       ctxsum, Wcp, bcp, out, 2,
                       ctxsum, Wcp, bcp, out, 2);
}

// Round 2
// 809.676 us; speedup vs baseline: 1.1019x; 1.0359x over previous
//
#include <hip/hip_runtime.h>

// ---------------------------------------------------------------------------
// AttentionLayer fused implementation for MI355X (gfx950)  -- Round 4
// D=H=1024, B=128, R=512, M=B*R=65536
//
// R4 changes vs R3 (theory: score_gemm latency-bound on COLD A-panel DMA --
// LLC/HBM latency ~600-900cy > one K-step of compute, so the 2-deep buffer's
// per-step barrier drain exposes ~450cy/step; MfmaUtil stuck at 21%):
//  * score_gemm_k: 3-deep LDS pipeline (48 KB) with counted vmcnt.
//    DMA for step k+2 issued during step k; `s_waitcnt vmcnt(4)` + raw
//    s_barrier per step (never vmcnt(0) in steady state) -> each DMA gets
//    ~2 full steps of latency coverage. Loop fully unrolled so all buffer
//    indices / LDS offsets are compile-time.
//  * ctx_k: reads Vb (bf16, 16B/lane) instead of V fp32 -> halves traffic.
//  * Fallback (small ws) path unchanged.
// ---------------------------------------------------------------------------

typedef __bf16 bf16x8 __attribute__((ext_vector_type(8)));
typedef float floatx4 __attribute__((ext_vector_type(4)));

__device__ __forceinline__ float tanh_fast(float x) {
    x = fminf(10.0f, fmaxf(-10.0f, x));
    float e = exp2f(x * 2.885390081777927f);
    return (e - 1.0f) * __builtin_amdgcn_rcpf(e + 1.0f);
}

// ---------------- K0: convert V fp32 -> bf16 ------------------------------
__global__ __launch_bounds__(256) void conv_k(
    const float* __restrict__ V, __bf16* __restrict__ Vb) {
    const size_t i = ((size_t)blockIdx.x * 256 + threadIdx.x) * 8;
    const float4 a = *reinterpret_cast<const float4*>(V + i);
    const float4 b = *reinterpret_cast<const float4*>(V + i + 4);
    bf16x8 o;
    o[0] = (__bf16)a.x; o[1] = (__bf16)a.y;
    o[2] = (__bf16)a.z; o[3] = (__bf16)a.w;
    o[4] = (__bf16)b.x; o[5] = (__bf16)b.y;
    o[6] = (__bf16)b.z; o[7] = (__bf16)b.w;
    *reinterpret_cast<bf16x8*>(Vb + i) = o;
}

// ---------------- K1: transpose + convert Wv -> WvT (bf16) ----------------
__global__ __launch_bounds__(256) void wvt_kernel(
    const float* __restrict__ Wv, __bf16* __restrict__ WvT) {
    __shared__ float tile[64][65];
    const int k0 = blockIdx.x * 64, n0 = blockIdx.y * 64;
    const int c = threadIdx.x & 63, r = threadIdx.x >> 6;  // 4 rows/pass
#pragma unroll
    for (int i = 0; i < 16; ++i)
        tile[r + i * 4][c] = Wv[(size_t)(k0 + r + i * 4) * 1024 + n0 + c];
    __syncthreads();
#pragma unroll
    for (int i = 0; i < 16; ++i)
        WvT[(size_t)(n0 + r + i * 4) * 1024 + k0 + c] =
            (__bf16)tile[c][r + i * 4];
}

// ---------------- small fp32 GEMM: C[128,1024] = act(A@W + b) -------------
__global__ __launch_bounds__(512) void small_gemm_k(
    const float* __restrict__ A0, const float* __restrict__ W0,
    const float* __restrict__ b0, float* __restrict__ C0, int act0,
    const float* __restrict__ A1, const float* __restrict__ W1,
    const float* __restrict__ b1, float* __restrict__ C1, int act1) {
    const float* A; const float* W; const float* bs; float* C; int act;
    if (blockIdx.z == 0) { A = A0; W = W0; bs = b0; C = C0; act = act0; }
    else                 { A = A1; W = W1; bs = b1; C = C1; act = act1; }
    __shared__ float red[3][8][128];
    const int tid = threadIdx.x;
    const int nl = tid & 127, kq = tid >> 7;
    const int n = blockIdx.x * 128 + nl;
    const int m0 = blockIdx.y * 8;
    const float* Ab = A + m0 * 1024;
    float acc[8] = {};
    const int kbeg = kq * 256, kend = kbeg + 256;
#pragma unroll 4
    for (int k = kbeg; k < kend; ++k) {
        float w = W[(size_t)k * 1024 + n];
#pragma unroll
        for (int mi = 0; mi < 8; ++mi)
            acc[mi] = fmaf(Ab[mi * 1024 + k], w, acc[mi]);
    }
    if (kq > 0) {
#pragma unroll
        for (int mi = 0; mi < 8; ++mi) red[kq - 1][mi][nl] = acc[mi];
    }
    __syncthreads();
    if (kq == 0) {
        float bias = bs[n];
#pragma unroll
        for (int mi = 0; mi < 8; ++mi) {
            float v = acc[mi] + red[0][mi][nl] + red[1][mi][nl] +
                      red[2][mi][nl] + bias;
            if (act == 1) v = fmaxf(v, 0.0f);
            else if (act == 2) v = tanh_fast(v);
            C[(size_t)(m0 + mi) * 1024 + n] = v;
        }
    }
}

// ---------------- K5: fused score GEMM (3-deep pipelined DMA) -------------
// 128x128 tile, BK=32, 4 waves x (64x64 via 4x4 mfma_f32_16x16x32_bf16).
// Both operands via global_load_lds w=16 into XOR-octet-swizzled linear LDS,
// 3 buffers. DMA(k+2) issued during step k; per-step `s_waitcnt vmcnt(4)`
// (= leave the newest 4 loads in flight) + raw s_barrier guarantees buf(k+1)
// complete while buf(k+2) stays in flight -> ~2 steps of latency coverage.
__global__ __launch_bounds__(256, 3) void score_gemm_k(
    const __bf16* __restrict__ Vb, const __bf16* __restrict__ WvT,
    const float* __restrict__ bv, const float* __restrict__ h_att,
    const float* __restrict__ Wal, float* __restrict__ scores) {
    __shared__ __bf16 As[3][128 * 32];   // 24 KB
    __shared__ __bf16 Bs[3][128 * 32];   // 24 KB

    const int tid = threadIdx.x;
    const int bid = blockIdx.x;
    const int xcd = bid & 7;
    const int j = bid >> 3;
    const int mtile = xcd * 64 + (j >> 3);   // 0..511
    const int ntile = j & 7;                 // 0..7
    const int m0 = mtile * 128, n0 = ntile * 128;
    const int wid = tid >> 6, lane = tid & 63;
    const int wm = wid & 1, wn = wid >> 1;
    const int lcol = lane & 15, quad = lane >> 4;

    floatx4 acc[4][4] = {};

    // granule g (0..511): row=g>>2, lds-octet=g&3, src-octet=(g&3)^((row>>1)&3)
    const int grow = tid >> 2;
    const int kg = (tid & 3) ^ ((grow >> 1) & 3);
    const __bf16* ap0 = Vb + (size_t)(m0 + grow) * 1024 + kg * 8;
    const __bf16* bp0 = WvT + (size_t)(n0 + grow) * 1024 + kg * 8;

    auto dma = [&](int buf, int k0) {
        __builtin_amdgcn_global_load_lds(
            (const __attribute__((address_space(1))) void*)(ap0 + k0),
            (__attribute__((address_space(3))) void*)(&As[buf][tid * 8]),
            16, 0, 0);
        __builtin_amdgcn_global_load_lds(
            (const __attribute__((address_space(1))) void*)(ap0 + 64 * 1024 + k0),
            (__attribute__((address_space(3))) void*)(&As[buf][(256 + tid) * 8]),
            16, 0, 0);
        __builtin_amdgcn_global_load_lds(
            (const __attribute__((address_space(1))) void*)(bp0 + k0),
            (__attribute__((address_space(3))) void*)(&Bs[buf][tid * 8]),
            16, 0, 0);
        __builtin_amdgcn_global_load_lds(
            (const __attribute__((address_space(1))) void*)(bp0 + 64 * 1024 + k0),
            (__attribute__((address_space(3))) void*)(&Bs[buf][(256 + tid) * 8]),
            16, 0, 0);
    };

    // ---- prologue: fill buffers 0 and 1
    dma(0, 0);
    dma(1, 32);

    // fragment LDS element offsets (row-swizzled octets), loop-invariant
    int aoff[4], boff[4];
#pragma unroll
    for (int i = 0; i < 4; ++i) {
        int r = wm * 64 + i * 16 + lcol;
        aoff[i] = r * 32 + ((quad ^ ((r >> 1) & 3)) * 8);
        int n = wn * 64 + i * 16 + lcol;
        boff[i] = n * 32 + ((quad ^ ((n >> 1) & 3)) * 8);
    }
    asm volatile("s_waitcnt vmcnt(4)" ::: "memory");  // buf0 complete
    __builtin_amdgcn_s_barrier();

#pragma unroll
    for (int kk = 0; kk < 32; ++kk) {
        const int cur = kk % 3;
        if (kk < 30) dma((kk + 2) % 3, (kk + 2) * 32);  // 2 steps ahead
        bf16x8 af[4], bfr[4];
#pragma unroll
        for (int i = 0; i < 4; ++i) {
            af[i] = *reinterpret_cast<const bf16x8*>(&As[cur][aoff[i]]);
            bfr[i] = *reinterpret_cast<const bf16x8*>(&Bs[cur][boff[i]]);
        }
#pragma unroll
        for (int mi = 0; mi < 4; ++mi)
#pragma unroll
            for (int ni = 0; ni < 4; ++ni)
                acc[mi][ni] = __builtin_amdgcn_mfma_f32_16x16x32_bf16(
                    af[mi], bfr[ni], acc[mi][ni], 0, 0, 0);
        if (kk < 30) {
            asm volatile("s_waitcnt vmcnt(4)" ::: "memory");  // buf(kk+1) done
            __builtin_amdgcn_s_barrier();
        } else if (kk == 30) {
            asm volatile("s_waitcnt vmcnt(0)" ::: "memory");  // last buffer
            __builtin_amdgcn_s_barrier();
        }
    }

    // ---- epilogue: fused score partials ----
    const int b = m0 >> 9;
    float wal[4], hat[4], bvv[4];
#pragma unroll
    for (int ni = 0; ni < 4; ++ni) {
        int n = n0 + wn * 64 + ni * 16 + lcol;
        wal[ni] = Wal[n];
        hat[ni] = h_att[b * 1024 + n];
        bvv[ni] = bv[n];
    }
    float p[16];
#pragma unroll
    for (int mi = 0; mi < 4; ++mi) {
#pragma unroll
        for (int rg = 0; rg < 4; ++rg) {
            float s = 0.f;
#pragma unroll
            for (int ni = 0; ni < 4; ++ni) {
                float x = acc[mi][ni][rg] + bvv[ni];
                x = fmaxf(x, 0.f);
                s = fmaf(wal[ni], tanh_fast(x + hat[ni]), s);
            }
            p[mi * 4 + rg] = s;
        }
    }
#pragma unroll
    for (int off = 1; off < 16; off <<= 1) {
#pragma unroll
        for (int i = 0; i < 16; ++i) p[i] += __shfl_xor(p[i], off, 64);
    }
    if (lcol == 0) {
#pragma unroll
        for (int mi = 0; mi < 4; ++mi)
#pragma unroll
            for (int rg = 0; rg < 4; ++rg) {
                int row = m0 + wm * 64 + mi * 16 + quad * 4 + rg;
                atomicAdd(&scores[b * 513 + (row & 511)], p[mi * 4 + rg]);
            }
    }
}

// ---------------- K5fb: register-staging fallback (fp32 V) ----------------
__global__ __launch_bounds__(256, 3) void score_gemm_fb(
    const float* __restrict__ V, const __bf16* __restrict__ WvT,
    const float* __restrict__ bv, const float* __restrict__ h_att,
    const float* __restrict__ Wal, float* __restrict__ scores) {
    __shared__ __bf16 As[2][128 * 40];
    __shared__ __bf16 Bs[2][128 * 32];

    const int tid = threadIdx.x;
    const int bid = blockIdx.x;
    const int xcd = bid & 7;
    const int j = bid >> 3;
    const int mtile = xcd * 64 + (j >> 3);
    const int ntile = j & 7;
    const int m0 = mtile * 128, n0 = ntile * 128;
    const int wid = tid >> 6, lane = tid & 63;
    const int wm = wid & 1, wn = wid >> 1;
    const int lcol = lane & 15, quad = lane >> 4;

    floatx4 acc[4][4] = {};

    const int am = tid >> 1;
    const int ak = (tid & 1) * 16;
    const float* aptr = V + (size_t)(m0 + am) * 1024 + ak;

    const int g0n = tid >> 2, g0ks = tid & 3;
    const int g1n = (256 + tid) >> 2, g1ks = tid & 3;
    const int g0kg = g0ks ^ ((g0n >> 1) & 3);
    const int g1kg = g1ks ^ ((g1n >> 1) & 3);
    const __bf16* bp0 = WvT + (size_t)(n0 + g0n) * 1024 + g0kg * 8;
    const __bf16* bp1 = WvT + (size_t)(n0 + g1n) * 1024 + g1kg * 8;

    auto stage_A = [&](int buf, float4 f0, float4 f1, float4 f2, float4 f3) {
        bf16x8 u0, u1;
        u0[0] = (__bf16)f0.x; u0[1] = (__bf16)f0.y;
        u0[2] = (__bf16)f0.z; u0[3] = (__bf16)f0.w;
        u0[4] = (__bf16)f1.x; u0[5] = (__bf16)f1.y;
        u0[6] = (__bf16)f1.z; u0[7] = (__bf16)f1.w;
        u1[0] = (__bf16)f2.x; u1[1] = (__bf16)f2.y;
        u1[2] = (__bf16)f2.z; u1[3] = (__bf16)f2.w;
        u1[4] = (__bf16)f3.x; u1[5] = (__bf16)f3.y;
        u1[6] = (__bf16)f3.z; u1[7] = (__bf16)f3.w;
        __bf16* awr = &As[buf][am * 40 + ak];
        *reinterpret_cast<bf16x8*>(awr) = u0;
        *reinterpret_cast<bf16x8*>(awr + 8) = u1;
    };
    auto dma_B = [&](int buf, int k0) {
        __builtin_amdgcn_global_load_lds(
            (const __attribute__((address_space(1))) void*)(bp0 + k0),
            (__attribute__((address_space(3))) void*)(&Bs[buf][tid * 8]),
            16, 0, 0);
        __builtin_amdgcn_global_load_lds(
            (const __attribute__((address_space(1))) void*)(bp1 + k0),
            (__attribute__((address_space(3))) void*)(&Bs[buf][(256 + tid) * 8]),
            16, 0, 0);
    };

    dma_B(0, 0);
    {
        const float4* fp = reinterpret_cast<const float4*>(aptr);
        stage_A(0, fp[0], fp[1], fp[2], fp[3]);
    }
    __syncthreads();

    for (int kk = 0; kk < 32; ++kk) {
        const int cur = kk & 1, nxt = cur ^ 1;
        float4 f0, f1, f2, f3;
        const bool pf = (kk < 31);
        if (pf) {
            dma_B(nxt, (kk + 1) * 32);
            const float4* fp =
                reinterpret_cast<const float4*>(aptr + (kk + 1) * 32);
            f0 = fp[0]; f1 = fp[1]; f2 = fp[2]; f3 = fp[3];
        }
        bf16x8 af[4], bfr[4];
#pragma unroll
        for (int mi = 0; mi < 4; ++mi)
            af[mi] = *reinterpret_cast<const bf16x8*>(
                &As[cur][(wm * 64 + mi * 16 + lcol) * 40 + quad * 8]);
#pragma unroll
        for (int ni = 0; ni < 4; ++ni) {
            int n = wn * 64 + ni * 16 + lcol;
            int ks = quad ^ ((n >> 1) & 3);
            bfr[ni] = *reinterpret_cast<const bf16x8*>(
                &Bs[cur][n * 32 + ks * 8]);
        }
#pragma unroll
        for (int mi = 0; mi < 4; ++mi)
#pragma unroll
            for (int ni = 0; ni < 4; ++ni)
                acc[mi][ni] = __builtin_amdgcn_mfma_f32_16x16x32_bf16(
                    af[mi], bfr[ni], acc[mi][ni], 0, 0, 0);
        if (pf) stage_A(nxt, f0, f1, f2, f3);
        __syncthreads();
    }

    const int b = m0 >> 9;
    float wal[4], hat[4], bvv[4];
#pragma unroll
    for (int ni = 0; ni < 4; ++ni) {
        int n = n0 + wn * 64 + ni * 16 + lcol;
        wal[ni] = Wal[n];
        hat[ni] = h_att[b * 1024 + n];
        bvv[ni] = bv[n];
    }
    float p[16];
#pragma unroll
    for (int mi = 0; mi < 4; ++mi) {
#pragma unroll
        for (int rg = 0; rg < 4; ++rg) {
            float s = 0.f;
#pragma unroll
            for (int ni = 0; ni < 4; ++ni) {
                float x = acc[mi][ni][rg] + bvv[ni];
                x = fmaxf(x, 0.f);
                s = fmaf(wal[ni], tanh_fast(x + hat[ni]), s);
            }
            p[mi * 4 + rg] = s;
        }
    }
#pragma unroll
    for (int off = 1; off < 16; off <<= 1) {
#pragma unroll
        for (int i = 0; i < 16; ++i) p[i] += __shfl_xor(p[i], off, 64);
    }
    if (lcol == 0) {
#pragma unroll
        for (int mi = 0; mi < 4; ++mi)
#pragma unroll
            for (int rg = 0; rg < 4; ++rg) {
                int row = m0 + wm * 64 + mi * 16 + quad * 4 + rg;
                atomicAdd(&scores[b * 513 + (row & 511)], p[mi * 4 + rg]);
            }
    }
}

// ---------------- K6: scores[b][512] from s_att/h_att ---------------------
__global__ __launch_bounds__(256) void lastrow_k(
    const float* __restrict__ s_att, const float* __restrict__ h_att,
    const float* __restrict__ Wal, float* __restrict__ scores) {
    int b = blockIdx.x, tid = threadIdx.x;
    float s = 0.f;
    for (int h = tid; h < 1024; h += 256)
        s += Wal[h] * tanh_fast(s_att[b * 1024 + h] + h_att[b * 1024 + h]);
#pragma unroll
    for (int off = 32; off >= 1; off >>= 1) s += __shfl_xor(s, off, 64);
    __shared__ float red[4];
    if ((tid & 63) == 0) red[tid >> 6] = s;
    __syncthreads();
    if (tid == 0) scores[b * 513 + 512] = red[0] + red[1] + red[2] + red[3];
}

// ---------------- K7: softmax over 513 ------------------------------------
__global__ __launch_bounds__(256) void softmax_k(
    const float* __restrict__ scores, float* __restrict__ alpha) {
    int b = blockIdx.x, tid = threadIdx.x;
    const float* s = scores + b * 513;
    float v0 = s[tid];
    float v1 = s[tid + 256];
    float v2 = (tid == 0) ? s[512] : -1e30f;
    float m = fmaxf(v0, fmaxf(v1, v2));
#pragma unroll
    for (int off = 32; off >= 1; off >>= 1) m = fmaxf(m, __shfl_xor(m, off, 64));
    __shared__ float red[4];
    int w = tid >> 6;
    if ((tid & 63) == 0) red[w] = m;
    __syncthreads();
    m = fmaxf(fmaxf(red[0], red[1]), fmaxf(red[2], red[3]));
    const float L2E = 1.4426950408889634f;
    float e0 = exp2f((v0 - m) * L2E);
    float e1 = exp2f((v1 - m) * L2E);
    float e2 = (tid == 0) ? exp2f((v2 - m) * L2E) : 0.f;
    float sum = e0 + e1 + e2;
#pragma unroll
    for (int off = 32; off >= 1; off >>= 1) sum += __shfl_xor(sum, off, 64);
    __syncthreads();
    if ((tid & 63) == 0) red[w] = sum;
    __syncthreads();
    sum = red[0] + red[1] + red[2] + red[3];
    float inv = 1.0f / sum;
    float* a = alpha + b * 513;
    a[tid] = e0 * inv;
    a[tid + 256] = e1 * inv;
    if (tid == 0) a[512] = e2 * inv;
}

// ---------------- K8: context + h_proj (bf16 V) ---------------------------
// grid (128,2): b, d-half (512 d's). tid&63 -> 8-elem bf16x8 slot,
// tid>>6 = r-quarter (128 rows). LDS reduce across r-quarters.
__global__ __launch_bounds__(256) void ctx_k(
    const __bf16* __restrict__ Vb, const float* __restrict__ alpha,
    const float* __restrict__ s_proj, const float* __restrict__ h_proj,
    float* __restrict__ ctxsum) {
    const int b = blockIdx.x, dq = blockIdx.y;
    const int tid = threadIdx.x;
    const int dl = tid & 63, rq = tid >> 6;
    __shared__ float sal[513];
    __shared__ float red[3][64][9];
    for (int i = tid; i < 513; i += 256) sal[i] = alpha[b * 513 + i];
    __syncthreads();
    const int d0 = dq * 512 + dl * 8;
    const __bf16* vp = Vb + ((size_t)b * 512 + rq * 128) * 1024 + d0;
    float a[8] = {};
#pragma unroll 4
    for (int r = 0; r < 128; ++r) {
        float al = sal[rq * 128 + r];
        bf16x8 vv = *reinterpret_cast<const bf16x8*>(vp + (size_t)r * 1024);
#pragma unroll
        for (int jj = 0; jj < 8; ++jj) a[jj] = fmaf(al, (float)vv[jj], a[jj]);
    }
    if (rq > 0) {
#pragma unroll
        for (int jj = 0; jj < 8; ++jj) red[rq - 1][dl][jj] = a[jj];
    }
    __syncthreads();
    if (rq == 0) {
#pragma unroll
        for (int q = 0; q < 3; ++q)
#pragma unroll
            for (int jj = 0; jj < 8; ++jj) a[jj] += red[q][dl][jj];
        float aR = sal[512];
        float4 sp0 = *reinterpret_cast<const float4*>(s_proj + b * 1024 + d0);
        float4 sp1 = *reinterpret_cast<const float4*>(s_proj + b * 1024 + d0 + 4);
        float4 hp0 = *reinterpret_cast<const float4*>(h_proj + b * 1024 + d0);
        float4 hp1 = *reinterpret_cast<const float4*>(h_proj + b * 1024 + d0 + 4);
        float4 o0, o1;
        o0.x = fmaf(aR, sp0.x, a[0]) + hp0.x;
        o0.y = fmaf(aR, sp0.y, a[1]) + hp0.y;
        o0.z = fmaf(aR, sp0.z, a[2]) + hp0.z;
        o0.w = fmaf(aR, sp0.w, a[3]) + hp0.w;
        o1.x = fmaf(aR, sp1.x, a[4]) + hp1.x;
        o1.y = fmaf(aR, sp1.y, a[5]) + hp1.y;
        o1.z = fmaf(aR, sp1.z, a[6]) + hp1.z;
        o1.w = fmaf(aR, sp1.w, a[7]) + hp1.w;
        *reinterpret_cast<float4*>(ctxsum + b * 1024 + d0) = o0;
        *reinterpret_cast<float4*>(ctxsum + b * 1024 + d0 + 4) = o1;
    }
}

// ---------------- K8fb: context + h_proj (fp32 V fallback) ----------------
__global__ __launch_bounds__(256) void ctx_fb(
    const float* __restrict__ V, const float* __restrict__ alpha,
    const float* __restrict__ s_proj, const float* __restrict__ h_proj,
    float* __restrict__ ctxsum) {
    const int b = blockIdx.x, dq = blockIdx.y;
    const int tid = threadIdx.x;
    const int dl = tid & 63, rq = tid >> 6;
    __shared__ float sal[513];
    __shared__ float red[3][64][4];
    for (int i = tid; i < 513; i += 256) sal[i] = alpha[b * 513 + i];
    __syncthreads();
    const int d0 = dq * 256 + dl * 4;
    const float* vp = V + ((size_t)b * 512 + rq * 128) * 1024 + d0;
    float a0 = 0, a1 = 0, a2 = 0, a3 = 0;
#pragma unroll 8
    for (int r = 0; r < 128; ++r) {
        float al = sal[rq * 128 + r];
        const float4 vv = *reinterpret_cast<const float4*>(vp + (size_t)r * 1024);
        a0 = fmaf(al, vv.x, a0); a1 = fmaf(al, vv.y, a1);
        a2 = fmaf(al, vv.z, a2); a3 = fmaf(al, vv.w, a3);
    }
    if (rq > 0) {
        red[rq - 1][dl][0] = a0; red[rq - 1][dl][1] = a1;
        red[rq - 1][dl][2] = a2; red[rq - 1][dl][3] = a3;
    }
    __syncthreads();
    if (rq == 0) {
#pragma unroll
        for (int q = 0; q < 3; ++q) {
            a0 += red[q][dl][0]; a1 += red[q][dl][1];
            a2 += red[q][dl][2]; a3 += red[q][dl][3];
        }
        float4 sp = *reinterpret_cast<const float4*>(s_proj + b * 1024 + d0);
        float4 hp = *reinterpret_cast<const float4*>(h_proj + b * 1024 + d0);
        float aR = sal[512];
        float4 o;
        o.x = fmaf(aR, sp.x, a0) + hp.x;
        o.y = fmaf(aR, sp.y, a1) + hp.y;
        o.z = fmaf(aR, sp.z, a2) + hp.z;
        o.w = fmaf(aR, sp.w, a3) + hp.w;
        *reinterpret_cast<float4*>(ctxsum + b * 1024 + d0) = o;
    }
}

// ---------------------------------------------------------------------------
extern "C" void kernel_launch(void* const* d_in, const int* in_sizes, int n_in,
                              void* d_out, int out_size, void* d_ws,
                              size_t ws_size, hipStream_t stream) {
    const float* V   = (const float*)d_in[0];
    const float* s_t = (const float*)d_in[1];
    const float* h_t = (const float*)d_in[2];
    const float* Wv  = (const float*)d_in[3];
    const float* bv  = (const float*)d_in[4];
    const float* Wsp = (const float*)d_in[5];
    const float* bsp = (const float*)d_in[6];
    const float* Wsa = (const float*)d_in[7];
    const float* bsa = (const float*)d_in[8];
    const float* Whp = (const float*)d_in[9];
    const float* bhp = (const float*)d_in[10];
    const float* Wha = (const float*)d_in[11];
    const float* bha = (const float*)d_in[12];
    const float* Wal = (const float*)d_in[13];
    // d_in[14] = bal: softmax-invariant constant -> dropped
    const float* Wcp = (const float*)d_in[15];
    const float* bcp = (const float*)d_in[16];
    float* out = (float*)d_out;

    const size_t VB_BYTES = (size_t)128 * 512 * 1024 * 2;  // 128 MB
    const size_t SMALL_BYTES = 5242880 + 64;               // ~5.25 MB tail
    const bool big = ws_size >= VB_BYTES + SMALL_BYTES;

    char* ws = (char*)d_ws;
    __bf16* Vb = (__bf16*)ws;                    // 128 MB (big path only)
    char* base = big ? (ws + VB_BYTES) : ws;
    __bf16* WvT   = (__bf16*)(base + 0);         // 2 MB
    float* s_proj = (float*)(base + 2097152);    // 512 KB
    float* h_proj = (float*)(base + 2621440);    // 512 KB
    float* s_att  = (float*)(base + 3145728);    // 512 KB
    float* h_att  = (float*)(base + 3670016);    // 512 KB
    float* scores = (float*)(base + 4194304);    // 262656 B
    float* alpha  = (float*)(base + 4456960);    // 262656 B
    float* ctxsum = (float*)(base + 4719616);    // 512 KB

    if (big)
        hipLaunchKernelGGL(conv_k, dim3(32768), dim3(256), 0, stream, V, Vb);
    hipLaunchKernelGGL(wvt_kernel, dim3(16, 16), dim3(256), 0, stream, Wv, WvT);
    hipLaunchKernelGGL(small_gemm_k, dim3(8, 16, 2), dim3(512), 0, stream,
                       s_t, Wsp, bsp, s_proj, 1,
                       h_t, Whp, bhp, h_proj, 2);
    hipLaunchKernelGGL(small_gemm_k, dim3(8, 16, 2), dim3(512), 0, stream,
                       s_proj, Wsa, bsa, s_att, 0,
                       h_proj, Wha, bha, h_att, 0);
    (void)hipMemsetAsync(scores, 0, 128 * 513 * sizeof(float), stream);
    if (big)
        hipLaunchKernelGGL(score_gemm_k, dim3(4096), dim3(256), 0, stream,
                           Vb, WvT, bv, h_att, Wal, scores);
    else
        hipLaunchKernelGGL(score_gemm_fb, dim3(4096), dim3(256), 0, stream,
                           V, WvT, bv, h_att, Wal, scores);
    hipLaunchKernelGGL(lastrow_k, dim3(128), dim3(256), 0, stream,
                       s_att, h_att, Wal, scores);
    hipLaunchKernelGGL(softmax_k, dim3(128), dim3(256), 0, stream,
                       scores, alpha);
    if (big)
        hipLaunchKernelGGL(ctx_k, dim3(128, 2), dim3(256), 0, stream,
                           Vb, alpha, s_proj, h_proj, ctxsum);
    else
        hipLaunchKernelGGL(ctx_fb, dim3(128, 4), dim3(256), 0, stream,
                           V, alpha, s_proj, h_proj, ctxsum);
    hipLaunchKernelGGL(small_gemm_k, dim3(8, 16, 1), dim3(512), 0, stream,
                       ctxsum, Wcp, bcp, out, 2,
                       ctxsum, Wcp, bcp, out, 2);
}

// Round 4
// 786.283 us; speedup vs baseline: 1.1347x; 1.0298x over previous
//
#include <hip/hip_runtime.h>

// ---------------------------------------------------------------------------
// AttentionLayer fused implementation for MI355X (gfx950)  -- Round 6
// D=H=1024, B=128, R=512, M=B*R=65536
//
// R6 = R4 (last passing, 809us) with EXACTLY ONE kernel changed:
//  * score_gemm_k: 128m x 256n tile, 512 threads / 8 waves (2m x 4n); each
//    wave runs the R3-proven 64x64 acc[4][4] body. Staging per K-step:
//    3 DMA/thread (24KB) feeding 128 MFMA -- 25% less DMA traffic, 33%
//    fewer DMA instrs, half the barriers per MFMA vs the 128x128 variant.
//    2-phase __syncthreads loop (proven); ~110 VGPR (R5's 256-thr/208-VGPR
//    variant crashed -- reverted to safe shape).
//  * small_gemm_k / ctx_k / lastrow_k / softmax_k: byte-identical to R4.
// ---------------------------------------------------------------------------

typedef __bf16 bf16x8 __attribute__((ext_vector_type(8)));
typedef float floatx4 __attribute__((ext_vector_type(4)));

__device__ __forceinline__ float tanh_fast(float x) {
    x = fminf(10.0f, fmaxf(-10.0f, x));
    float e = exp2f(x * 2.885390081777927f);
    return (e - 1.0f) * __builtin_amdgcn_rcpf(e + 1.0f);
}

// ---------------- K0: convert V fp32 -> bf16 ------------------------------
__global__ __launch_bounds__(256) void conv_k(
    const float* __restrict__ V, __bf16* __restrict__ Vb) {
    const size_t i = ((size_t)blockIdx.x * 256 + threadIdx.x) * 8;
    const float4 a = *reinterpret_cast<const float4*>(V + i);
    const float4 b = *reinterpret_cast<const float4*>(V + i + 4);
    bf16x8 o;
    o[0] = (__bf16)a.x; o[1] = (__bf16)a.y;
    o[2] = (__bf16)a.z; o[3] = (__bf16)a.w;
    o[4] = (__bf16)b.x; o[5] = (__bf16)b.y;
    o[6] = (__bf16)b.z; o[7] = (__bf16)b.w;
    *reinterpret_cast<bf16x8*>(Vb + i) = o;
}

// ---------------- K1: transpose + convert Wv -> WvT (bf16) ----------------
__global__ __launch_bounds__(256) void wvt_kernel(
    const float* __restrict__ Wv, __bf16* __restrict__ WvT) {
    __shared__ float tile[64][65];
    const int k0 = blockIdx.x * 64, n0 = blockIdx.y * 64;
    const int c = threadIdx.x & 63, r = threadIdx.x >> 6;  // 4 rows/pass
#pragma unroll
    for (int i = 0; i < 16; ++i)
        tile[r + i * 4][c] = Wv[(size_t)(k0 + r + i * 4) * 1024 + n0 + c];
    __syncthreads();
#pragma unroll
    for (int i = 0; i < 16; ++i)
        WvT[(size_t)(n0 + r + i * 4) * 1024 + k0 + c] =
            (__bf16)tile[c][r + i * 4];
}

// ---------------- small fp32 GEMM: C[128,1024] = act(A@W + b) -------------
__global__ __launch_bounds__(512) void small_gemm_k(
    const float* __restrict__ A0, const float* __restrict__ W0,
    const float* __restrict__ b0, float* __restrict__ C0, int act0,
    const float* __restrict__ A1, const float* __restrict__ W1,
    const float* __restrict__ b1, float* __restrict__ C1, int act1) {
    const float* A; const float* W; const float* bs; float* C; int act;
    if (blockIdx.z == 0) { A = A0; W = W0; bs = b0; C = C0; act = act0; }
    else                 { A = A1; W = W1; bs = b1; C = C1; act = act1; }
    __shared__ float red[3][8][128];
    const int tid = threadIdx.x;
    const int nl = tid & 127, kq = tid >> 7;
    const int n = blockIdx.x * 128 + nl;
    const int m0 = blockIdx.y * 8;
    const float* Ab = A + m0 * 1024;
    float acc[8] = {};
    const int kbeg = kq * 256, kend = kbeg + 256;
#pragma unroll 4
    for (int k = kbeg; k < kend; ++k) {
        float w = W[(size_t)k * 1024 + n];
#pragma unroll
        for (int mi = 0; mi < 8; ++mi)
            acc[mi] = fmaf(Ab[mi * 1024 + k], w, acc[mi]);
    }
    if (kq > 0) {
#pragma unroll
        for (int mi = 0; mi < 8; ++mi) red[kq - 1][mi][nl] = acc[mi];
    }
    __syncthreads();
    if (kq == 0) {
        float bias = bs[n];
#pragma unroll
        for (int mi = 0; mi < 8; ++mi) {
            float v = acc[mi] + red[0][mi][nl] + red[1][mi][nl] +
                      red[2][mi][nl] + bias;
            if (act == 1) v = fmaxf(v, 0.0f);
            else if (act == 2) v = tanh_fast(v);
            C[(size_t)(m0 + mi) * 1024 + n] = v;
        }
    }
}

// ---------------- K5: fused score GEMM (128x256 tile, 8 waves) ------------
// 128m x 256n tile, BK=32, 512 threads = 8 waves in 2m x 4n grid; each wave
// computes 64x64 via the R3-proven 4x4 mfma_f32_16x16x32_bf16 body.
// Both operands staged via global_load_lds w=16 into XOR-octet-swizzled
// linear LDS, double-buffered 2-phase loop. Per K-step: 24KB DMA (3 loads/
// thread) feeding 128 MFMA -- 25% less staging per FLOP than 128x128.
// Epilogue folds bv/relu/h_att/tanh/Wal-dot, shuffle-reduces 16 n-lanes,
// atomicAdds into scores.
__global__ __launch_bounds__(512, 2) void score_gemm_k(
    const __bf16* __restrict__ Vb, const __bf16* __restrict__ WvT,
    const float* __restrict__ bv, const float* __restrict__ h_att,
    const float* __restrict__ Wal, float* __restrict__ scores) {
    __shared__ __bf16 As[2][128 * 32];   // 8 KB / buf
    __shared__ __bf16 Bs[2][256 * 32];   // 16 KB / buf -> 48 KB total

    const int tid = threadIdx.x;
    const int bid = blockIdx.x;
    const int xcd = bid & 7;
    const int j = bid >> 3;                  // 0..255
    const int mtile = xcd * 64 + (j >> 2);   // 0..511
    const int ntile = j & 3;                 // 0..3
    const int m0 = mtile * 128, n0 = ntile * 256;
    const int wid = tid >> 6, lane = tid & 63;
    const int wm = wid & 1, wn = wid >> 1;   // 2m x 4n wave grid
    const int lcol = lane & 15, quad = lane >> 4;

    floatx4 acc[4][4] = {};

    // granule g: row=g>>2, lds-octet=g&3, src-octet=(g&3)^((row>>1)&3).
    // tid covers granules 0..511 (rows 0..127); B adds granules 512..1023
    // (rows 128..255, +128 rows keeps (row>>1)&3 unchanged: 64%4==0).
    const int grow = tid >> 2;               // 0..127
    const int kg = (tid & 3) ^ ((tid >> 3) & 3);
    const __bf16* ap0 = Vb + (size_t)(m0 + grow) * 1024 + kg * 8;
    const __bf16* bp0 = WvT + (size_t)(n0 + grow) * 1024 + kg * 8;

    auto dma = [&](int buf, int k0) {
        __builtin_amdgcn_global_load_lds(
            (const __attribute__((address_space(1))) void*)(ap0 + k0),
            (__attribute__((address_space(3))) void*)(&As[buf][tid * 8]),
            16, 0, 0);
        __builtin_amdgcn_global_load_lds(
            (const __attribute__((address_space(1))) void*)(bp0 + k0),
            (__attribute__((address_space(3))) void*)(&Bs[buf][tid * 8]),
            16, 0, 0);
        __builtin_amdgcn_global_load_lds(
            (const __attribute__((address_space(1))) void*)(bp0 + 128 * 1024 + k0),
            (__attribute__((address_space(3))) void*)(&Bs[buf][(512 + tid) * 8]),
            16, 0, 0);
    };

    // fragment LDS element offsets (row-swizzled octets), loop-invariant
    int aoff[4], boff[4];
#pragma unroll
    for (int i = 0; i < 4; ++i) {
        int r = wm * 64 + i * 16 + lcol;
        aoff[i] = r * 32 + ((quad ^ ((r >> 1) & 3)) * 8);
        int n = wn * 64 + i * 16 + lcol;           // wn in 0..3 -> n in 0..255
        boff[i] = n * 32 + ((quad ^ ((n >> 1) & 3)) * 8);
    }

    dma(0, 0);
    __syncthreads();

    for (int kk = 0; kk < 32; ++kk) {
        const int cur = kk & 1;
        if (kk < 31) dma(cur ^ 1, (kk + 1) * 32);   // next step, in flight
        bf16x8 af[4], bfr[4];
#pragma unroll
        for (int i = 0; i < 4; ++i) {
            af[i] = *reinterpret_cast<const bf16x8*>(&As[cur][aoff[i]]);
            bfr[i] = *reinterpret_cast<const bf16x8*>(&Bs[cur][boff[i]]);
        }
#pragma unroll
        for (int mi = 0; mi < 4; ++mi)
#pragma unroll
            for (int ni = 0; ni < 4; ++ni)
                acc[mi][ni] = __builtin_amdgcn_mfma_f32_16x16x32_bf16(
                    af[mi], bfr[ni], acc[mi][ni], 0, 0, 0);
        __syncthreads();   // drains next-step DMA + role barrier
    }

    // ---- epilogue: fused score partials ----
    const int b = m0 >> 9;
    float wal[4], hat[4], bvv[4];
#pragma unroll
    for (int ni = 0; ni < 4; ++ni) {
        int n = n0 + wn * 64 + ni * 16 + lcol;
        wal[ni] = Wal[n];
        hat[ni] = h_att[b * 1024 + n];
        bvv[ni] = bv[n];
    }
    float p[16];
#pragma unroll
    for (int mi = 0; mi < 4; ++mi) {
#pragma unroll
        for (int rg = 0; rg < 4; ++rg) {
            float s = 0.f;
#pragma unroll
            for (int ni = 0; ni < 4; ++ni) {
                float x = acc[mi][ni][rg] + bvv[ni];
                x = fmaxf(x, 0.f);
                s = fmaf(wal[ni], tanh_fast(x + hat[ni]), s);
            }
            p[mi * 4 + rg] = s;
        }
    }
#pragma unroll
    for (int off = 1; off < 16; off <<= 1) {
#pragma unroll
        for (int i = 0; i < 16; ++i) p[i] += __shfl_xor(p[i], off, 64);
    }
    if (lcol == 0) {
#pragma unroll
        for (int mi = 0; mi < 4; ++mi)
#pragma unroll
            for (int rg = 0; rg < 4; ++rg) {
                int row = m0 + wm * 64 + mi * 16 + quad * 4 + rg;
                atomicAdd(&scores[b * 513 + (row & 511)], p[mi * 4 + rg]);
            }
    }
}

// ---------------- K5fb: register-staging fallback (fp32 V) ----------------
__global__ __launch_bounds__(256, 3) void score_gemm_fb(
    const float* __restrict__ V, const __bf16* __restrict__ WvT,
    const float* __restrict__ bv, const float* __restrict__ h_att,
    const float* __restrict__ Wal, float* __restrict__ scores) {
    __shared__ __bf16 As[2][128 * 40];
    __shared__ __bf16 Bs[2][128 * 32];

    const int tid = threadIdx.x;
    const int bid = blockIdx.x;
    const int xcd = bid & 7;
    const int j = bid >> 3;
    const int mtile = xcd * 64 + (j >> 3);
    const int ntile = j & 7;
    const int m0 = mtile * 128, n0 = ntile * 128;
    const int wid = tid >> 6, lane = tid & 63;
    const int wm = wid & 1, wn = wid >> 1;
    const int lcol = lane & 15, quad = lane >> 4;

    floatx4 acc[4][4] = {};

    const int am = tid >> 1;
    const int ak = (tid & 1) * 16;
    const float* aptr = V + (size_t)(m0 + am) * 1024 + ak;

    const int g0n = tid >> 2, g0ks = tid & 3;
    const int g1n = (256 + tid) >> 2, g1ks = tid & 3;
    const int g0kg = g0ks ^ ((g0n >> 1) & 3);
    const int g1kg = g1ks ^ ((g1n >> 1) & 3);
    const __bf16* bp0 = WvT + (size_t)(n0 + g0n) * 1024 + g0kg * 8;
    const __bf16* bp1 = WvT + (size_t)(n0 + g1n) * 1024 + g1kg * 8;

    auto stage_A = [&](int buf, float4 f0, float4 f1, float4 f2, float4 f3) {
        bf16x8 u0, u1;
        u0[0] = (__bf16)f0.x; u0[1] = (__bf16)f0.y;
        u0[2] = (__bf16)f0.z; u0[3] = (__bf16)f0.w;
        u0[4] = (__bf16)f1.x; u0[5] = (__bf16)f1.y;
        u0[6] = (__bf16)f1.z; u0[7] = (__bf16)f1.w;
        u1[0] = (__bf16)f2.x; u1[1] = (__bf16)f2.y;
        u1[2] = (__bf16)f2.z; u1[3] = (__bf16)f2.w;
        u1[4] = (__bf16)f3.x; u1[5] = (__bf16)f3.y;
        u1[6] = (__bf16)f3.z; u1[7] = (__bf16)f3.w;
        __bf16* awr = &As[buf][am * 40 + ak];
        *reinterpret_cast<bf16x8*>(awr) = u0;
        *reinterpret_cast<bf16x8*>(awr + 8) = u1;
    };
    auto dma_B = [&](int buf, int k0) {
        __builtin_amdgcn_global_load_lds(
            (const __attribute__((address_space(1))) void*)(bp0 + k0),
            (__attribute__((address_space(3))) void*)(&Bs[buf][tid * 8]),
            16, 0, 0);
        __builtin_amdgcn_global_load_lds(
            (const __attribute__((address_space(1))) void*)(bp1 + k0),
            (__attribute__((address_space(3))) void*)(&Bs[buf][(256 + tid) * 8]),
            16, 0, 0);
    };

    dma_B(0, 0);
    {
        const float4* fp = reinterpret_cast<const float4*>(aptr);
        stage_A(0, fp[0], fp[1], fp[2], fp[3]);
    }
    __syncthreads();

    for (int kk = 0; kk < 32; ++kk) {
        const int cur = kk & 1, nxt = cur ^ 1;
        float4 f0, f1, f2, f3;
        const bool pf = (kk < 31);
        if (pf) {
            dma_B(nxt, (kk + 1) * 32);
            const float4* fp =
                reinterpret_cast<const float4*>(aptr + (kk + 1) * 32);
            f0 = fp[0]; f1 = fp[1]; f2 = fp[2]; f3 = fp[3];
        }
        bf16x8 af[4], bfr[4];
#pragma unroll
        for (int mi = 0; mi < 4; ++mi)
            af[mi] = *reinterpret_cast<const bf16x8*>(
                &As[cur][(wm * 64 + mi * 16 + lcol) * 40 + quad * 8]);
#pragma unroll
        for (int ni = 0; ni < 4; ++ni) {
            int n = wn * 64 + ni * 16 + lcol;
            int ks = quad ^ ((n >> 1) & 3);
            bfr[ni] = *reinterpret_cast<const bf16x8*>(
                &Bs[cur][n * 32 + ks * 8]);
        }
#pragma unroll
        for (int mi = 0; mi < 4; ++mi)
#pragma unroll
            for (int ni = 0; ni < 4; ++ni)
                acc[mi][ni] = __builtin_amdgcn_mfma_f32_16x16x32_bf16(
                    af[mi], bfr[ni], acc[mi][ni], 0, 0, 0);
        if (pf) stage_A(nxt, f0, f1, f2, f3);
        __syncthreads();
    }

    const int b = m0 >> 9;
    float wal[4], hat[4], bvv[4];
#pragma unroll
    for (int ni = 0; ni < 4; ++ni) {
        int n = n0 + wn * 64 + ni * 16 + lcol;
        wal[ni] = Wal[n];
        hat[ni] = h_att[b * 1024 + n];
        bvv[ni] = bv[n];
    }
    float p[16];
#pragma unroll
    for (int mi = 0; mi < 4; ++mi) {
#pragma unroll
        for (int rg = 0; rg < 4; ++rg) {
            float s = 0.f;
#pragma unroll
            for (int ni = 0; ni < 4; ++ni) {
                float x = acc[mi][ni][rg] + bvv[ni];
                x = fmaxf(x, 0.f);
                s = fmaf(wal[ni], tanh_fast(x + hat[ni]), s);
            }
            p[mi * 4 + rg] = s;
        }
    }
#pragma unroll
    for (int off = 1; off < 16; off <<= 1) {
#pragma unroll
        for (int i = 0; i < 16; ++i) p[i] += __shfl_xor(p[i], off, 64);
    }
    if (lcol == 0) {
#pragma unroll
        for (int mi = 0; mi < 4; ++mi)
#pragma unroll
            for (int rg = 0; rg < 4; ++rg) {
                int row = m0 + wm * 64 + mi * 16 + quad * 4 + rg;
                atomicAdd(&scores[b * 513 + (row & 511)], p[mi * 4 + rg]);
            }
    }
}

// ---------------- K6: scores[b][512] from s_att/h_att ---------------------
__global__ __launch_bounds__(256) void lastrow_k(
    const float* __restrict__ s_att, const float* __restrict__ h_att,
    const float* __restrict__ Wal, float* __restrict__ scores) {
    int b = blockIdx.x, tid = threadIdx.x;
    float s = 0.f;
    for (int h = tid; h < 1024; h += 256)
        s += Wal[h] * tanh_fast(s_att[b * 1024 + h] + h_att[b * 1024 + h]);
#pragma unroll
    for (int off = 32; off >= 1; off >>= 1) s += __shfl_xor(s, off, 64);
    __shared__ float red[4];
    if ((tid & 63) == 0) red[tid >> 6] = s;
    __syncthreads();
    if (tid == 0) scores[b * 513 + 512] = red[0] + red[1] + red[2] + red[3];
}

// ---------------- K7: softmax over 513 ------------------------------------
__global__ __launch_bounds__(256) void softmax_k(
    const float* __restrict__ scores, float* __restrict__ alpha) {
    int b = blockIdx.x, tid = threadIdx.x;
    const float* s = scores + b * 513;
    float v0 = s[tid];
    float v1 = s[tid + 256];
    float v2 = (tid == 0) ? s[512] : -1e30f;
    float m = fmaxf(v0, fmaxf(v1, v2));
#pragma unroll
    for (int off = 32; off >= 1; off >>= 1) m = fmaxf(m, __shfl_xor(m, off, 64));
    __shared__ float red[4];
    int w = tid >> 6;
    if ((tid & 63) == 0) red[w] = m;
    __syncthreads();
    m = fmaxf(fmaxf(red[0], red[1]), fmaxf(red[2], red[3]));
    const float L2E = 1.4426950408889634f;
    float e0 = exp2f((v0 - m) * L2E);
    float e1 = exp2f((v1 - m) * L2E);
    float e2 = (tid == 0) ? exp2f((v2 - m) * L2E) : 0.f;
    float sum = e0 + e1 + e2;
#pragma unroll
    for (int off = 32; off >= 1; off >>= 1) sum += __shfl_xor(sum, off, 64);
    __syncthreads();
    if ((tid & 63) == 0) red[w] = sum;
    __syncthreads();
    sum = red[0] + red[1] + red[2] + red[3];
    float inv = 1.0f / sum;
    float* a = alpha + b * 513;
    a[tid] = e0 * inv;
    a[tid + 256] = e1 * inv;
    if (tid == 0) a[512] = e2 * inv;
}

// ---------------- K8: context + h_proj (bf16 V) ---------------------------
__global__ __launch_bounds__(256) void ctx_k(
    const __bf16* __restrict__ Vb, const float* __restrict__ alpha,
    const float* __restrict__ s_proj, const float* __restrict__ h_proj,
    float* __restrict__ ctxsum) {
    const int b = blockIdx.x, dq = blockIdx.y;
    const int tid = threadIdx.x;
    const int dl = tid & 63, rq = tid >> 6;
    __shared__ float sal[513];
    __shared__ float red[3][64][9];
    for (int i = tid; i < 513; i += 256) sal[i] = alpha[b * 513 + i];
    __syncthreads();
    const int d0 = dq * 512 + dl * 8;
    const __bf16* vp = Vb + ((size_t)b * 512 + rq * 128) * 1024 + d0;
    float a[8] = {};
#pragma unroll 4
    for (int r = 0; r < 128; ++r) {
        float al = sal[rq * 128 + r];
        bf16x8 vv = *reinterpret_cast<const bf16x8*>(vp + (size_t)r * 1024);
#pragma unroll
        for (int jj = 0; jj < 8; ++jj) a[jj] = fmaf(al, (float)vv[jj], a[jj]);
    }
    if (rq > 0) {
#pragma unroll
        for (int jj = 0; jj < 8; ++jj) red[rq - 1][dl][jj] = a[jj];
    }
    __syncthreads();
    if (rq == 0) {
#pragma unroll
        for (int q = 0; q < 3; ++q)
#pragma unroll
            for (int jj = 0; jj < 8; ++jj) a[jj] += red[q][dl][jj];
        float aR = sal[512];
        float4 sp0 = *reinterpret_cast<const float4*>(s_proj + b * 1024 + d0);
        float4 sp1 = *reinterpret_cast<const float4*>(s_proj + b * 1024 + d0 + 4);
        float4 hp0 = *reinterpret_cast<const float4*>(h_proj + b * 1024 + d0);
        float4 hp1 = *reinterpret_cast<const float4*>(h_proj + b * 1024 + d0 + 4);
        float4 o0, o1;
        o0.x = fmaf(aR, sp0.x, a[0]) + hp0.x;
        o0.y = fmaf(aR, sp0.y, a[1]) + hp0.y;
        o0.z = fmaf(aR, sp0.z, a[2]) + hp0.z;
        o0.w = fmaf(aR, sp0.w, a[3]) + hp0.w;
        o1.x = fmaf(aR, sp1.x, a[4]) + hp1.x;
        o1.y = fmaf(aR, sp1.y, a[5]) + hp1.y;
        o1.z = fmaf(aR, sp1.z, a[6]) + hp1.z;
        o1.w = fmaf(aR, sp1.w, a[7]) + hp1.w;
        *reinterpret_cast<float4*>(ctxsum + b * 1024 + d0) = o0;
        *reinterpret_cast<float4*>(ctxsum + b * 1024 + d0 + 4) = o1;
    }
}

// ---------------- K8fb: context + h_proj (fp32 V fallback) ----------------
__global__ __launch_bounds__(256) void ctx_fb(
    const float* __restrict__ V, const float* __restrict__ alpha,
    const float* __restrict__ s_proj, const float* __restrict__ h_proj,
    float* __restrict__ ctxsum) {
    const int b = blockIdx.x, dq = blockIdx.y;
    const int tid = threadIdx.x;
    const int dl = tid & 63, rq = tid >> 6;
    __shared__ float sal[513];
    __shared__ float red[3][64][4];
    for (int i = tid; i < 513; i += 256) sal[i] = alpha[b * 513 + i];
    __syncthreads();
    const int d0 = dq * 256 + dl * 4;
    const float* vp = V + ((size_t)b * 512 + rq * 128) * 1024 + d0;
    float a0 = 0, a1 = 0, a2 = 0, a3 = 0;
#pragma unroll 8
    for (int r = 0; r < 128; ++r) {
        float al = sal[rq * 128 + r];
        const float4 vv = *reinterpret_cast<const float4*>(vp + (size_t)r * 1024);
        a0 = fmaf(al, vv.x, a0); a1 = fmaf(al, vv.y, a1);
        a2 = fmaf(al, vv.z, a2); a3 = fmaf(al, vv.w, a3);
    }
    if (rq > 0) {
        red[rq - 1][dl][0] = a0; red[rq - 1][dl][1] = a1;
        red[rq - 1][dl][2] = a2; red[rq - 1][dl][3] = a3;
    }
    __syncthreads();
    if (rq == 0) {
#pragma unroll
        for (int q = 0; q < 3; ++q) {
            a0 += red[q][dl][0]; a1 += red[q][dl][1];
            a2 += red[q][dl][2]; a3 += red[q][dl][3];
        }
        float4 sp = *reinterpret_cast<const float4*>(s_proj + b * 1024 + d0);
        float4 hp = *reinterpret_cast<const float4*>(h_proj + b * 1024 + d0);
        float aR = sal[512];
        float4 o;
        o.x = fmaf(aR, sp.x, a0) + hp.x;
        o.y = fmaf(aR, sp.y, a1) + hp.y;
        o.z = fmaf(aR, sp.z, a2) + hp.z;
        o.w = fmaf(aR, sp.w, a3) + hp.w;
        *reinterpret_cast<float4*>(ctxsum + b * 1024 + d0) = o;
    }
}

// ---------------------------------------------------------------------------
extern "C" void kernel_launch(void* const* d_in, const int* in_sizes, int n_in,
                              void* d_out, int out_size, void* d_ws,
                              size_t ws_size, hipStream_t stream) {
    const float* V   = (const float*)d_in[0];
    const float* s_t = (const float*)d_in[1];
    const float* h_t = (const float*)d_in[2];
    const float* Wv  = (const float*)d_in[3];
    const float* bv  = (const float*)d_in[4];
    const float* Wsp = (const float*)d_in[5];
    const float* bsp = (const float*)d_in[6];
    const float* Wsa = (const float*)d_in[7];
    const float* bsa = (const float*)d_in[8];
    const float* Whp = (const float*)d_in[9];
    const float* bhp = (const float*)d_in[10];
    const float* Wha = (const float*)d_in[11];
    const float* bha = (const float*)d_in[12];
    const float* Wal = (const float*)d_in[13];
    // d_in[14] = bal: softmax-invariant constant -> dropped
    const float* Wcp = (const float*)d_in[15];
    const float* bcp = (const float*)d_in[16];
    float* out = (float*)d_out;

    const size_t VB_BYTES = (size_t)128 * 512 * 1024 * 2;  // 128 MB
    const size_t SMALL_BYTES = 5242880 + 64;               // ~5.25 MB tail
    const bool big = ws_size >= VB_BYTES + SMALL_BYTES;

    char* ws = (char*)d_ws;
    __bf16* Vb = (__bf16*)ws;                    // 128 MB (big path only)
    char* base = big ? (ws + VB_BYTES) : ws;
    __bf16* WvT   = (__bf16*)(base + 0);         // 2 MB
    float* s_proj = (float*)(base + 2097152);    // 512 KB
    float* h_proj = (float*)(base + 2621440);    // 512 KB
    float* s_att  = (float*)(base + 3145728);    // 512 KB
    float* h_att  = (float*)(base + 3670016);    // 512 KB
    float* scores = (float*)(base + 4194304);    // 262656 B
    float* alpha  = (float*)(base + 4456960);    // 262656 B
    float* ctxsum = (float*)(base + 4719616);    // 512 KB

    if (big)
        hipLaunchKernelGGL(conv_k, dim3(32768), dim3(256), 0, stream, V, Vb);
    hipLaunchKernelGGL(wvt_kernel, dim3(16, 16), dim3(256), 0, stream, Wv, WvT);
    hipLaunchKernelGGL(small_gemm_k, dim3(8, 16, 2), dim3(512), 0, stream,
                       s_t, Wsp, bsp, s_proj, 1,
                       h_t, Whp, bhp, h_proj, 2);
    hipLaunchKernelGGL(small_gemm_k, dim3(8, 16, 2), dim3(512), 0, stream,
                       s_proj, Wsa, bsa, s_att, 0,
                       h_proj, Wha, bha, h_att, 0);
    (void)hipMemsetAsync(scores, 0, 128 * 513 * sizeof(float), stream);
    if (big)
        hipLaunchKernelGGL(score_gemm_k, dim3(2048), dim3(512), 0, stream,
                           Vb, WvT, bv, h_att, Wal, scores);
    else
        hipLaunchKernelGGL(score_gemm_fb, dim3(4096), dim3(256), 0, stream,
                           V, WvT, bv, h_att, Wal, scores);
    hipLaunchKernelGGL(lastrow_k, dim3(128), dim3(256), 0, stream,
                       s_att, h_att, Wal, scores);
    hipLaunchKernelGGL(softmax_k, dim3(128), dim3(256), 0, stream,
                       scores, alpha);
    if (big)
        hipLaunchKernelGGL(ctx_k, dim3(128, 2), dim3(256), 0, stream,
                           Vb, alpha, s_proj, h_proj, ctxsum);
    else
        hipLaunchKernelGGL(ctx_fb, dim3(128, 4), dim3(256), 0, stream,
                           V, alpha, s_proj, h_proj, ctxsum);
    hipLaunchKernelGGL(small_gemm_k, dim3(8, 16, 1), dim3(512), 0, stream,
                       ctxsum, Wcp, bcp, out, 2,
                       ctxsum, Wcp, bcp, out, 2);
}

// Round 5
// 775.571 us; speedup vs baseline: 1.1503x; 1.0138x over previous
//
#include <hip/hip_runtime.h>

// ---------------------------------------------------------------------------
// AttentionLayer fused implementation for MI355X (gfx950)  -- Round 7
// D=H=1024, B=128, R=512, M=B*R=65536
//
// R7 = R6 (passing, 786us) with EXACTLY ONE kernel changed:
//  * score_gemm_k: m201-style 8-phase-per-2-K-tiles schedule (here: 4 phases
//    per BK=64 K-tile). 256x256 tile, 512 thr / 8 waves (2m x 4n), per-wave
//    128x64 output acc[8][4]. LDS 128KB: [2 buf][2 kslice][256 rows][32 k]
//    per operand, proven octet swizzle within each 32-k slice.
//    Per phase: {ds_read 4-8 x b128 | issue one 16KB staging chunk |
//    raw s_barrier | lgkmcnt(0) | setprio(1) 16 MFMA setprio(0) |
//    raw s_barrier}. vmcnt(4) ONLY at phases 0/2 (2 chunks stay in flight).
//    LDS-read/MFMA drops 512 -> 384 B/MFMA (A-frags reused across n-strip).
//  * all other kernels byte-identical to R6.
// ---------------------------------------------------------------------------

typedef __bf16 bf16x8 __attribute__((ext_vector_type(8)));
typedef float floatx4 __attribute__((ext_vector_type(4)));

__device__ __forceinline__ float tanh_fast(float x) {
    x = fminf(10.0f, fmaxf(-10.0f, x));
    float e = exp2f(x * 2.885390081777927f);
    return (e - 1.0f) * __builtin_amdgcn_rcpf(e + 1.0f);
}

// ---------------- K0: convert V fp32 -> bf16 ------------------------------
__global__ __launch_bounds__(256) void conv_k(
    const float* __restrict__ V, __bf16* __restrict__ Vb) {
    const size_t i = ((size_t)blockIdx.x * 256 + threadIdx.x) * 8;
    const float4 a = *reinterpret_cast<const float4*>(V + i);
    const float4 b = *reinterpret_cast<const float4*>(V + i + 4);
    bf16x8 o;
    o[0] = (__bf16)a.x; o[1] = (__bf16)a.y;
    o[2] = (__bf16)a.z; o[3] = (__bf16)a.w;
    o[4] = (__bf16)b.x; o[5] = (__bf16)b.y;
    o[6] = (__bf16)b.z; o[7] = (__bf16)b.w;
    *reinterpret_cast<bf16x8*>(Vb + i) = o;
}

// ---------------- K1: transpose + convert Wv -> WvT (bf16) ----------------
__global__ __launch_bounds__(256) void wvt_kernel(
    const float* __restrict__ Wv, __bf16* __restrict__ WvT) {
    __shared__ float tile[64][65];
    const int k0 = blockIdx.x * 64, n0 = blockIdx.y * 64;
    const int c = threadIdx.x & 63, r = threadIdx.x >> 6;  // 4 rows/pass
#pragma unroll
    for (int i = 0; i < 16; ++i)
        tile[r + i * 4][c] = Wv[(size_t)(k0 + r + i * 4) * 1024 + n0 + c];
    __syncthreads();
#pragma unroll
    for (int i = 0; i < 16; ++i)
        WvT[(size_t)(n0 + r + i * 4) * 1024 + k0 + c] =
            (__bf16)tile[c][r + i * 4];
}

// ---------------- small fp32 GEMM: C[128,1024] = act(A@W + b) -------------
__global__ __launch_bounds__(512) void small_gemm_k(
    const float* __restrict__ A0, const float* __restrict__ W0,
    const float* __restrict__ b0, float* __restrict__ C0, int act0,
    const float* __restrict__ A1, const float* __restrict__ W1,
    const float* __restrict__ b1, float* __restrict__ C1, int act1) {
    const float* A; const float* W; const float* bs; float* C; int act;
    if (blockIdx.z == 0) { A = A0; W = W0; bs = b0; C = C0; act = act0; }
    else                 { A = A1; W = W1; bs = b1; C = C1; act = act1; }
    __shared__ float red[3][8][128];
    const int tid = threadIdx.x;
    const int nl = tid & 127, kq = tid >> 7;
    const int n = blockIdx.x * 128 + nl;
    const int m0 = blockIdx.y * 8;
    const float* Ab = A + m0 * 1024;
    float acc[8] = {};
    const int kbeg = kq * 256, kend = kbeg + 256;
#pragma unroll 4
    for (int k = kbeg; k < kend; ++k) {
        float w = W[(size_t)k * 1024 + n];
#pragma unroll
        for (int mi = 0; mi < 8; ++mi)
            acc[mi] = fmaf(Ab[mi * 1024 + k], w, acc[mi]);
    }
    if (kq > 0) {
#pragma unroll
        for (int mi = 0; mi < 8; ++mi) red[kq - 1][mi][nl] = acc[mi];
    }
    __syncthreads();
    if (kq == 0) {
        float bias = bs[n];
#pragma unroll
        for (int mi = 0; mi < 8; ++mi) {
            float v = acc[mi] + red[0][mi][nl] + red[1][mi][nl] +
                      red[2][mi][nl] + bias;
            if (act == 1) v = fmaxf(v, 0.0f);
            else if (act == 2) v = tanh_fast(v);
            C[(size_t)(m0 + mi) * 1024 + n] = v;
        }
    }
}

// ---------------- K5: fused score GEMM (256x256, 4-phase counted-vmcnt) ---
__global__ __launch_bounds__(512, 1) void score_gemm_k(
    const __bf16* __restrict__ Vb, const __bf16* __restrict__ WvT,
    const float* __restrict__ bv, const float* __restrict__ h_att,
    const float* __restrict__ Wal, float* __restrict__ scores) {
    // [buf 2][kslice 2][256 rows][32 k] per operand = 64 KB each
    __shared__ __bf16 As[32768];
    __shared__ __bf16 Bs[32768];

    const int tid = threadIdx.x;
    const int bid = blockIdx.x;                  // 1024 blocks
    const int xcd = bid & 7;
    const int j = bid >> 3;                      // 0..127
    const int mtile = xcd * 32 + (j >> 2);       // 0..255
    const int ntile = j & 3;                     // 0..3
    const int m0 = mtile * 256, n0 = ntile * 256;
    const int wid = tid >> 6, lane = tid & 63;
    const int wm = wid & 1, wn = wid >> 1;       // 2m x 4n wave grid
    const int lcol = lane & 15, quad = lane >> 4;

    floatx4 acc[8][4] = {};

    // staging granule map (proven): granule g: row=g>>2, lds-octet=g&3,
    // src-octet=(g&3)^((row>>1)&3). Thread covers g=tid and g=512+tid
    // (row+128 keeps the octet xor unchanged).
    const int grow = tid >> 2;                   // 0..127
    const int kg = (tid & 3) ^ ((tid >> 3) & 3);
    const __bf16* apA = Vb + (size_t)(m0 + grow) * 1024 + kg * 8;
    const __bf16* apB = WvT + (size_t)(n0 + grow) * 1024 + kg * 8;

    auto dmaA = [&](int nb, int ks, int k0) {
        const __bf16* s = apA + k0 + ks * 32;
        __bf16* d = &As[(nb * 2 + ks) * 8192 + tid * 8];
        __builtin_amdgcn_global_load_lds(
            (const __attribute__((address_space(1))) void*)s,
            (__attribute__((address_space(3))) void*)d, 16, 0, 0);
        __builtin_amdgcn_global_load_lds(
            (const __attribute__((address_space(1))) void*)(s + 128 * 1024),
            (__attribute__((address_space(3))) void*)(d + 4096), 16, 0, 0);
    };
    auto dmaB = [&](int nb, int ks, int k0) {
        const __bf16* s = apB + k0 + ks * 32;
        __bf16* d = &Bs[(nb * 2 + ks) * 8192 + tid * 8];
        __builtin_amdgcn_global_load_lds(
            (const __attribute__((address_space(1))) void*)s,
            (__attribute__((address_space(3))) void*)d, 16, 0, 0);
        __builtin_amdgcn_global_load_lds(
            (const __attribute__((address_space(1))) void*)(s + 128 * 1024),
            (__attribute__((address_space(3))) void*)(d + 4096), 16, 0, 0);
    };

    // fragment LDS element offsets within a [256][32] slice (octet-swizzled)
    int aoff[8], boff[4];
#pragma unroll
    for (int i = 0; i < 8; ++i) {
        int r = wm * 128 + i * 16 + lcol;
        aoff[i] = r * 32 + ((quad ^ ((r >> 1) & 3)) * 8);
    }
#pragma unroll
    for (int i = 0; i < 4; ++i) {
        int n = wn * 64 + i * 16 + lcol;
        boff[i] = n * 32 + ((quad ^ ((n >> 1) & 3)) * 8);
    }

    // ---- prologue: stage K-tile 0 into buf 0 (issue order = consume order)
    dmaA(0, 0, 0);
    dmaB(0, 0, 0);
    dmaA(0, 1, 0);
    dmaB(0, 1, 0);

#define LD_A(dst, base, i) \
    dst = *reinterpret_cast<const bf16x8*>(&As[(base) + aoff[i]])
#define LD_B(dst, base, i) \
    dst = *reinterpret_cast<const bf16x8*>(&Bs[(base) + boff[i]])
#define MFMA16(M0)                                                        \
    __builtin_amdgcn_s_setprio(1);                                        \
    _Pragma("unroll") for (int ni = 0; ni < 4; ++ni) {                    \
        acc[M0 + 0][ni] = __builtin_amdgcn_mfma_f32_16x16x32_bf16(        \
            a0, bf[ni], acc[M0 + 0][ni], 0, 0, 0);                        \
        acc[M0 + 1][ni] = __builtin_amdgcn_mfma_f32_16x16x32_bf16(        \
            a1, bf[ni], acc[M0 + 1][ni], 0, 0, 0);                        \
        acc[M0 + 2][ni] = __builtin_amdgcn_mfma_f32_16x16x32_bf16(        \
            a2, bf[ni], acc[M0 + 2][ni], 0, 0, 0);                        \
        acc[M0 + 3][ni] = __builtin_amdgcn_mfma_f32_16x16x32_bf16(        \
            a3, bf[ni], acc[M0 + 3][ni], 0, 0, 0);                        \
    }                                                                     \
    __builtin_amdgcn_s_setprio(0);

#pragma unroll 2
    for (int t = 0; t < 16; ++t) {
        const int buf = t & 1, nbuf = buf ^ 1;
        const int kn = ((t < 15) ? (t + 1) : 15) * 64;  // clamped prefetch k
        const int asb0 = (buf * 2) * 8192, asb1 = asb0 + 8192;
        bf16x8 a0, a1, a2, a3, bf[4];

        // ---- phase 0: ks0, m-frags 0..3 (reads chunks A-ks0, B-ks0)
        asm volatile("s_waitcnt vmcnt(4)" ::: "memory");
        LD_A(a0, asb0, 0); LD_A(a1, asb0, 1);
        LD_A(a2, asb0, 2); LD_A(a3, asb0, 3);
        LD_B(bf[0], asb0, 0); LD_B(bf[1], asb0, 1);
        LD_B(bf[2], asb0, 2); LD_B(bf[3], asb0, 3);
        dmaA(nbuf, 0, kn);
        __builtin_amdgcn_s_barrier();
        asm volatile("s_waitcnt lgkmcnt(0)" ::: "memory");
        MFMA16(0)
        __builtin_amdgcn_s_barrier();

        // ---- phase 1: ks0, m-frags 4..7 (B reused)
        LD_A(a0, asb0, 4); LD_A(a1, asb0, 5);
        LD_A(a2, asb0, 6); LD_A(a3, asb0, 7);
        dmaB(nbuf, 0, kn);
        __builtin_amdgcn_s_barrier();
        asm volatile("s_waitcnt lgkmcnt(0)" ::: "memory");
        MFMA16(4)
        __builtin_amdgcn_s_barrier();

        // ---- phase 2: ks1, m-frags 0..3 (reads chunks A-ks1, B-ks1)
        asm volatile("s_waitcnt vmcnt(4)" ::: "memory");
        LD_A(a0, asb1, 0); LD_A(a1, asb1, 1);
        LD_A(a2, asb1, 2); LD_A(a3, asb1, 3);
        LD_B(bf[0], asb1, 0); LD_B(bf[1], asb1, 1);
        LD_B(bf[2], asb1, 2); LD_B(bf[3], asb1, 3);
        dmaA(nbuf, 1, kn);
        __builtin_amdgcn_s_barrier();
        asm volatile("s_waitcnt lgkmcnt(0)" ::: "memory");
        MFMA16(0)
        __builtin_amdgcn_s_barrier();

        // ---- phase 3: ks1, m-frags 4..7 (B reused)
        LD_A(a0, asb1, 4); LD_A(a1, asb1, 5);
        LD_A(a2, asb1, 6); LD_A(a3, asb1, 7);
        dmaB(nbuf, 1, kn);
        __builtin_amdgcn_s_barrier();
        asm volatile("s_waitcnt lgkmcnt(0)" ::: "memory");
        MFMA16(4)
        __builtin_amdgcn_s_barrier();
    }
#undef LD_A
#undef LD_B
#undef MFMA16

    // ---- epilogue: fused score partials ----
    const int b = m0 >> 9;
    float wal[4], hat[4], bvv[4];
#pragma unroll
    for (int ni = 0; ni < 4; ++ni) {
        int n = n0 + wn * 64 + ni * 16 + lcol;
        wal[ni] = Wal[n];
        hat[ni] = h_att[b * 1024 + n];
        bvv[ni] = bv[n];
    }
    float p[32];
#pragma unroll
    for (int mi = 0; mi < 8; ++mi) {
#pragma unroll
        for (int rg = 0; rg < 4; ++rg) {
            float s = 0.f;
#pragma unroll
            for (int ni = 0; ni < 4; ++ni) {
                float x = acc[mi][ni][rg] + bvv[ni];
                x = fmaxf(x, 0.f);
                s = fmaf(wal[ni], tanh_fast(x + hat[ni]), s);
            }
            p[mi * 4 + rg] = s;
        }
    }
#pragma unroll
    for (int off = 1; off < 16; off <<= 1) {
#pragma unroll
        for (int i = 0; i < 32; ++i) p[i] += __shfl_xor(p[i], off, 64);
    }
    if (lcol == 0) {
#pragma unroll
        for (int mi = 0; mi < 8; ++mi)
#pragma unroll
            for (int rg = 0; rg < 4; ++rg) {
                int row = m0 + wm * 128 + mi * 16 + quad * 4 + rg;
                atomicAdd(&scores[b * 513 + (row & 511)], p[mi * 4 + rg]);
            }
    }
}

// ---------------- K5fb: register-staging fallback (fp32 V) ----------------
__global__ __launch_bounds__(256, 3) void score_gemm_fb(
    const float* __restrict__ V, const __bf16* __restrict__ WvT,
    const float* __restrict__ bv, const float* __restrict__ h_att,
    const float* __restrict__ Wal, float* __restrict__ scores) {
    __shared__ __bf16 As[2][128 * 40];
    __shared__ __bf16 Bs[2][128 * 32];

    const int tid = threadIdx.x;
    const int bid = blockIdx.x;
    const int xcd = bid & 7;
    const int j = bid >> 3;
    const int mtile = xcd * 64 + (j >> 3);
    const int ntile = j & 7;
    const int m0 = mtile * 128, n0 = ntile * 128;
    const int wid = tid >> 6, lane = tid & 63;
    const int wm = wid & 1, wn = wid >> 1;
    const int lcol = lane & 15, quad = lane >> 4;

    floatx4 acc[4][4] = {};

    const int am = tid >> 1;
    const int ak = (tid & 1) * 16;
    const float* aptr = V + (size_t)(m0 + am) * 1024 + ak;

    const int g0n = tid >> 2, g0ks = tid & 3;
    const int g1n = (256 + tid) >> 2, g1ks = tid & 3;
    const int g0kg = g0ks ^ ((g0n >> 1) & 3);
    const int g1kg = g1ks ^ ((g1n >> 1) & 3);
    const __bf16* bp0 = WvT + (size_t)(n0 + g0n) * 1024 + g0kg * 8;
    const __bf16* bp1 = WvT + (size_t)(n0 + g1n) * 1024 + g1kg * 8;

    auto stage_A = [&](int buf, float4 f0, float4 f1, float4 f2, float4 f3) {
        bf16x8 u0, u1;
        u0[0] = (__bf16)f0.x; u0[1] = (__bf16)f0.y;
        u0[2] = (__bf16)f0.z; u0[3] = (__bf16)f0.w;
        u0[4] = (__bf16)f1.x; u0[5] = (__bf16)f1.y;
        u0[6] = (__bf16)f1.z; u0[7] = (__bf16)f1.w;
        u1[0] = (__bf16)f2.x; u1[1] = (__bf16)f2.y;
        u1[2] = (__bf16)f2.z; u1[3] = (__bf16)f2.w;
        u1[4] = (__bf16)f3.x; u1[5] = (__bf16)f3.y;
        u1[6] = (__bf16)f3.z; u1[7] = (__bf16)f3.w;
        __bf16* awr = &As[buf][am * 40 + ak];
        *reinterpret_cast<bf16x8*>(awr) = u0;
        *reinterpret_cast<bf16x8*>(awr + 8) = u1;
    };
    auto dma_B = [&](int buf, int k0) {
        __builtin_amdgcn_global_load_lds(
            (const __attribute__((address_space(1))) void*)(bp0 + k0),
            (__attribute__((address_space(3))) void*)(&Bs[buf][tid * 8]),
            16, 0, 0);
        __builtin_amdgcn_global_load_lds(
            (const __attribute__((address_space(1))) void*)(bp1 + k0),
            (__attribute__((address_space(3))) void*)(&Bs[buf][(256 + tid) * 8]),
            16, 0, 0);
    };

    dma_B(0, 0);
    {
        const float4* fp = reinterpret_cast<const float4*>(aptr);
        stage_A(0, fp[0], fp[1], fp[2], fp[3]);
    }
    __syncthreads();

    for (int kk = 0; kk < 32; ++kk) {
        const int cur = kk & 1, nxt = cur ^ 1;
        float4 f0, f1, f2, f3;
        const bool pf = (kk < 31);
        if (pf) {
            dma_B(nxt, (kk + 1) * 32);
            const float4* fp =
                reinterpret_cast<const float4*>(aptr + (kk + 1) * 32);
            f0 = fp[0]; f1 = fp[1]; f2 = fp[2]; f3 = fp[3];
        }
        bf16x8 af[4], bfr[4];
#pragma unroll
        for (int mi = 0; mi < 4; ++mi)
            af[mi] = *reinterpret_cast<const bf16x8*>(
                &As[cur][(wm * 64 + mi * 16 + lcol) * 40 + quad * 8]);
#pragma unroll
        for (int ni = 0; ni < 4; ++ni) {
            int n = wn * 64 + ni * 16 + lcol;
            int ks = quad ^ ((n >> 1) & 3);
            bfr[ni] = *reinterpret_cast<const bf16x8*>(
                &Bs[cur][n * 32 + ks * 8]);
        }
#pragma unroll
        for (int mi = 0; mi < 4; ++mi)
#pragma unroll
            for (int ni = 0; ni < 4; ++ni)
                acc[mi][ni] = __builtin_amdgcn_mfma_f32_16x16x32_bf16(
                    af[mi], bfr[ni], acc[mi][ni], 0, 0, 0);
        if (pf) stage_A(nxt, f0, f1, f2, f3);
        __syncthreads();
    }

    const int b = m0 >> 9;
    float wal[4], hat[4], bvv[4];
#pragma unroll
    for (int ni = 0; ni < 4; ++ni) {
        int n = n0 + wn * 64 + ni * 16 + lcol;
        wal[ni] = Wal[n];
        hat[ni] = h_att[b * 1024 + n];
        bvv[ni] = bv[n];
    }
    float p[16];
#pragma unroll
    for (int mi = 0; mi < 4; ++mi) {
#pragma unroll
        for (int rg = 0; rg < 4; ++rg) {
            float s = 0.f;
#pragma unroll
            for (int ni = 0; ni < 4; ++ni) {
                float x = acc[mi][ni][rg] + bvv[ni];
                x = fmaxf(x, 0.f);
                s = fmaf(wal[ni], tanh_fast(x + hat[ni]), s);
            }
            p[mi * 4 + rg] = s;
        }
    }
#pragma unroll
    for (int off = 1; off < 16; off <<= 1) {
#pragma unroll
        for (int i = 0; i < 16; ++i) p[i] += __shfl_xor(p[i], off, 64);
    }
    if (lcol == 0) {
#pragma unroll
        for (int mi = 0; mi < 4; ++mi)
#pragma unroll
            for (int rg = 0; rg < 4; ++rg) {
                int row = m0 + wm * 64 + mi * 16 + quad * 4 + rg;
                atomicAdd(&scores[b * 513 + (row & 511)], p[mi * 4 + rg]);
            }
    }
}

// ---------------- K6: scores[b][512] from s_att/h_att ---------------------
__global__ __launch_bounds__(256) void lastrow_k(
    const float* __restrict__ s_att, const float* __restrict__ h_att,
    const float* __restrict__ Wal, float* __restrict__ scores) {
    int b = blockIdx.x, tid = threadIdx.x;
    float s = 0.f;
    for (int h = tid; h < 1024; h += 256)
        s += Wal[h] * tanh_fast(s_att[b * 1024 + h] + h_att[b * 1024 + h]);
#pragma unroll
    for (int off = 32; off >= 1; off >>= 1) s += __shfl_xor(s, off, 64);
    __shared__ float red[4];
    if ((tid & 63) == 0) red[tid >> 6] = s;
    __syncthreads();
    if (tid == 0) scores[b * 513 + 512] = red[0] + red[1] + red[2] + red[3];
}

// ---------------- K7: softmax over 513 ------------------------------------
__global__ __launch_bounds__(256) void softmax_k(
    const float* __restrict__ scores, float* __restrict__ alpha) {
    int b = blockIdx.x, tid = threadIdx.x;
    const float* s = scores + b * 513;
    float v0 = s[tid];
    float v1 = s[tid + 256];
    float v2 = (tid == 0) ? s[512] : -1e30f;
    float m = fmaxf(v0, fmaxf(v1, v2));
#pragma unroll
    for (int off = 32; off >= 1; off >>= 1) m = fmaxf(m, __shfl_xor(m, off, 64));
    __shared__ float red[4];
    int w = tid >> 6;
    if ((tid & 63) == 0) red[w] = m;
    __syncthreads();
    m = fmaxf(fmaxf(red[0], red[1]), fmaxf(red[2], red[3]));
    const float L2E = 1.4426950408889634f;
    float e0 = exp2f((v0 - m) * L2E);
    float e1 = exp2f((v1 - m) * L2E);
    float e2 = (tid == 0) ? exp2f((v2 - m) * L2E) : 0.f;
    float sum = e0 + e1 + e2;
#pragma unroll
    for (int off = 32; off >= 1; off >>= 1) sum += __shfl_xor(sum, off, 64);
    __syncthreads();
    if ((tid & 63) == 0) red[w] = sum;
    __syncthreads();
    sum = red[0] + red[1] + red[2] + red[3];
    float inv = 1.0f / sum;
    float* a = alpha + b * 513;
    a[tid] = e0 * inv;
    a[tid + 256] = e1 * inv;
    if (tid == 0) a[512] = e2 * inv;
}

// ---------------- K8: context + h_proj (bf16 V) ---------------------------
__global__ __launch_bounds__(256) void ctx_k(
    const __bf16* __restrict__ Vb, const float* __restrict__ alpha,
    const float* __restrict__ s_proj, const float* __restrict__ h_proj,
    float* __restrict__ ctxsum) {
    const int b = blockIdx.x, dq = blockIdx.y;
    const int tid = threadIdx.x;
    const int dl = tid & 63, rq = tid >> 6;
    __shared__ float sal[513];
    __shared__ float red[3][64][9];
    for (int i = tid; i < 513; i += 256) sal[i] = alpha[b * 513 + i];
    __syncthreads();
    const int d0 = dq * 512 + dl * 8;
    const __bf16* vp = Vb + ((size_t)b * 512 + rq * 128) * 1024 + d0;
    float a[8] = {};
#pragma unroll 4
    for (int r = 0; r < 128; ++r) {
        float al = sal[rq * 128 + r];
        bf16x8 vv = *reinterpret_cast<const bf16x8*>(vp + (size_t)r * 1024);
#pragma unroll
        for (int jj = 0; jj < 8; ++jj) a[jj] = fmaf(al, (float)vv[jj], a[jj]);
    }
    if (rq > 0) {
#pragma unroll
        for (int jj = 0; jj < 8; ++jj) red[rq - 1][dl][jj] = a[jj];
    }
    __syncthreads();
    if (rq == 0) {
#pragma unroll
        for (int q = 0; q < 3; ++q)
#pragma unroll
            for (int jj = 0; jj < 8; ++jj) a[jj] += red[q][dl][jj];
        float aR = sal[512];
        float4 sp0 = *reinterpret_cast<const float4*>(s_proj + b * 1024 + d0);
        float4 sp1 = *reinterpret_cast<const float4*>(s_proj + b * 1024 + d0 + 4);
        float4 hp0 = *reinterpret_cast<const float4*>(h_proj + b * 1024 + d0);
        float4 hp1 = *reinterpret_cast<const float4*>(h_proj + b * 1024 + d0 + 4);
        float4 o0, o1;
        o0.x = fmaf(aR, sp0.x, a[0]) + hp0.x;
        o0.y = fmaf(aR, sp0.y, a[1]) + hp0.y;
        o0.z = fmaf(aR, sp0.z, a[2]) + hp0.z;
        o0.w = fmaf(aR, sp0.w, a[3]) + hp0.w;
        o1.x = fmaf(aR, sp1.x, a[4]) + hp1.x;
        o1.y = fmaf(aR, sp1.y, a[5]) + hp1.y;
        o1.z = fmaf(aR, sp1.z, a[6]) + hp1.z;
        o1.w = fmaf(aR, sp1.w, a[7]) + hp1.w;
        *reinterpret_cast<float4*>(ctxsum + b * 1024 + d0) = o0;
        *reinterpret_cast<float4*>(ctxsum + b * 1024 + d0 + 4) = o1;
    }
}

// ---------------- K8fb: context + h_proj (fp32 V fallback) ----------------
__global__ __launch_bounds__(256) void ctx_fb(
    const float* __restrict__ V, const float* __restrict__ alpha,
    const float* __restrict__ s_proj, const float* __restrict__ h_proj,
    float* __restrict__ ctxsum) {
    const int b = blockIdx.x, dq = blockIdx.y;
    const int tid = threadIdx.x;
    const int dl = tid & 63, rq = tid >> 6;
    __shared__ float sal[513];
    __shared__ float red[3][64][4];
    for (int i = tid; i < 513; i += 256) sal[i] = alpha[b * 513 + i];
    __syncthreads();
    const int d0 = dq * 256 + dl * 4;
    const float* vp = V + ((size_t)b * 512 + rq * 128) * 1024 + d0;
    float a0 = 0, a1 = 0, a2 = 0, a3 = 0;
#pragma unroll 8
    for (int r = 0; r < 128; ++r) {
        float al = sal[rq * 128 + r];
        const float4 vv = *reinterpret_cast<const float4*>(vp + (size_t)r * 1024);
        a0 = fmaf(al, vv.x, a0); a1 = fmaf(al, vv.y, a1);
        a2 = fmaf(al, vv.z, a2); a3 = fmaf(al, vv.w, a3);
    }
    if (rq > 0) {
        red[rq - 1][dl][0] = a0; red[rq - 1][dl][1] = a1;
        red[rq - 1][dl][2] = a2; red[rq - 1][dl][3] = a3;
    }
    __syncthreads();
    if (rq == 0) {
#pragma unroll
        for (int q = 0; q < 3; ++q) {
            a0 += red[q][dl][0]; a1 += red[q][dl][1];
            a2 += red[q][dl][2]; a3 += red[q][dl][3];
        }
        float4 sp = *reinterpret_cast<const float4*>(s_proj + b * 1024 + d0);
        float4 hp = *reinterpret_cast<const float4*>(h_proj + b * 1024 + d0);
        float aR = sal[512];
        float4 o;
        o.x = fmaf(aR, sp.x, a0) + hp.x;
        o.y = fmaf(aR, sp.y, a1) + hp.y;
        o.z = fmaf(aR, sp.z, a2) + hp.z;
        o.w = fmaf(aR, sp.w, a3) + hp.w;
        *reinterpret_cast<float4*>(ctxsum + b * 1024 + d0) = o;
    }
}

// ---------------------------------------------------------------------------
extern "C" void kernel_launch(void* const* d_in, const int* in_sizes, int n_in,
                              void* d_out, int out_size, void* d_ws,
                              size_t ws_size, hipStream_t stream) {
    const float* V   = (const float*)d_in[0];
    const float* s_t = (const float*)d_in[1];
    const float* h_t = (const float*)d_in[2];
    const float* Wv  = (const float*)d_in[3];
    const float* bv  = (const float*)d_in[4];
    const float* Wsp = (const float*)d_in[5];
    const float* bsp = (const float*)d_in[6];
    const float* Wsa = (const float*)d_in[7];
    const float* bsa = (const float*)d_in[8];
    const float* Whp = (const float*)d_in[9];
    const float* bhp = (const float*)d_in[10];
    const float* Wha = (const float*)d_in[11];
    const float* bha = (const float*)d_in[12];
    const float* Wal = (const float*)d_in[13];
    // d_in[14] = bal: softmax-invariant constant -> dropped
    const float* Wcp = (const float*)d_in[15];
    const float* bcp = (const float*)d_in[16];
    float* out = (float*)d_out;

    const size_t VB_BYTES = (size_t)128 * 512 * 1024 * 2;  // 128 MB
    const size_t SMALL_BYTES = 5242880 + 64;               // ~5.25 MB tail
    const bool big = ws_size >= VB_BYTES + SMALL_BYTES;

    char* ws = (char*)d_ws;
    __bf16* Vb = (__bf16*)ws;                    // 128 MB (big path only)
    char* base = big ? (ws + VB_BYTES) : ws;
    __bf16* WvT   = (__bf16*)(base + 0);         // 2 MB
    float* s_proj = (float*)(base + 2097152);    // 512 KB
    float* h_proj = (float*)(base + 2621440);    // 512 KB
    float* s_att  = (float*)(base + 3145728);    // 512 KB
    float* h_att  = (float*)(base + 3670016);    // 512 KB
    float* scores = (float*)(base + 4194304);    // 262656 B
    float* alpha  = (float*)(base + 4456960);    // 262656 B
    float* ctxsum = (float*)(base + 4719616);    // 512 KB

    if (big)
        hipLaunchKernelGGL(conv_k, dim3(32768), dim3(256), 0, stream, V, Vb);
    hipLaunchKernelGGL(wvt_kernel, dim3(16, 16), dim3(256), 0, stream, Wv, WvT);
    hipLaunchKernelGGL(small_gemm_k, dim3(8, 16, 2), dim3(512), 0, stream,
                       s_t, Wsp, bsp, s_proj, 1,
                       h_t, Whp, bhp, h_proj, 2);
    hipLaunchKernelGGL(small_gemm_k, dim3(8, 16, 2), dim3(512), 0, stream,
                       s_proj, Wsa, bsa, s_att, 0,
                       h_proj, Wha, bha, h_att, 0);
    (void)hipMemsetAsync(scores, 0, 128 * 513 * sizeof(float), stream);
    if (big)
        hipLaunchKernelGGL(score_gemm_k, dim3(1024), dim3(512), 0, stream,
                           Vb, WvT, bv, h_att, Wal, scores);
    else
        hipLaunchKernelGGL(score_gemm_fb, dim3(4096), dim3(256), 0, stream,
                           V, WvT, bv, h_att, Wal, scores);
    hipLaunchKernelGGL(lastrow_k, dim3(128), dim3(256), 0, stream,
                       s_att, h_att, Wal, scores);
    hipLaunchKernelGGL(softmax_k, dim3(128), dim3(256), 0, stream,
                       scores, alpha);
    if (big)
        hipLaunchKernelGGL(ctx_k, dim3(128, 2), dim3(256), 0, stream,
                           Vb, alpha, s_proj, h_proj, ctxsum);
    else
        hipLaunchKernelGGL(ctx_fb, dim3(128, 4), dim3(256), 0, stream,
                           V, alpha, s_proj, h_proj, ctxsum);
    hipLaunchKernelGGL(small_gemm_k, dim3(8, 16, 1), dim3(512), 0, stream,
                       ctxsum, Wcp, bcp, out, 2,
                       ctxsum, Wcp, bcp, out, 2);
}